// Round 1
// baseline (547.025 us; speedup 1.0000x reference)
//
#include <hip/hip_runtime.h>
#include <hip/hip_bf16.h>
#include <math.h>

#define N 20000
#define E 160000
#define MUL 64
#define EDIM 8
#define NZ 4

#define INV_SQRT_MUL 0.125f          // 1/sqrt(64)
#define INV_E 0.35355339059327373f   // 1/sqrt(8)
#define INV_N 0.35355339059327373f   // 1/sqrt(8)
#define INV2 0.08838834764831845f    // 1/sqrt(128)
#define INV_SC 0.0625f               // 1/sqrt(256)
#define INV_SQRT3 0.5773502691896258f

__device__ __forceinline__ float silu(float v) {
    return v / (1.0f + __expf(-v));
}

// ---------------------------------------------------------------------------
// Kernel 1: per-node linear (lin1).  4 nodes per 256-thread block.
// h0[n][v] = inv * sum_u x0[n][u] * W0[u][v]
// h1 stored [n][d][v] (d-major, coalesced): inv * sum_u x1[n][u][d] * W1[u][v]
// ---------------------------------------------------------------------------
__global__ __launch_bounds__(256) void k_node_pre(
    const float* __restrict__ x,
    const float* __restrict__ W0, const float* __restrict__ W1,
    float* __restrict__ h0, float* __restrict__ h1)
{
    const int tid = threadIdx.x;
    const int n0 = blockIdx.x * 4;
    __shared__ float xrow[4][256];
    for (int i = tid; i < 1024; i += 256) {
        int t = i >> 8, c = i & 255;
        xrow[t][c] = x[(size_t)(n0 + t) * 256 + c];
    }
    __syncthreads();
    const int v = tid & 63;
    const int part = tid >> 6;
    float acc[4] = {0.f, 0.f, 0.f, 0.f};
    if (part == 0) {
        for (int u = 0; u < 64; ++u) {
            float wv = W0[u * 64 + v];
            #pragma unroll
            for (int t = 0; t < 4; ++t) acc[t] += xrow[t][u] * wv;
        }
        #pragma unroll
        for (int t = 0; t < 4; ++t)
            h0[(size_t)(n0 + t) * 64 + v] = acc[t] * INV_SQRT_MUL;
    } else {
        const int d = part - 1;
        for (int u = 0; u < 64; ++u) {
            float wv = W1[u * 64 + v];
            #pragma unroll
            for (int t = 0; t < 4; ++t) acc[t] += xrow[t][64 + u * 3 + d] * wv;
        }
        #pragma unroll
        for (int t = 0; t < 4; ++t)
            h1[(size_t)(n0 + t) * 192 + d * 64 + v] = acc[t] * INV_SQRT_MUL;
    }
}

// ---------------------------------------------------------------------------
// Kernel 2: per-edge MLP + messages + atomic scatter.
// One wave (64 lanes) per edge, 4 edges per 256-thread block.
// s0 layout [n][128]; s1 layout [n][d][128] (d-major so atomics coalesce).
// ---------------------------------------------------------------------------
__global__ __launch_bounds__(256) void k_edge(
    const int* __restrict__ eidx,
    const float* __restrict__ eattr, const float* __restrict__ eemb,
    const float* __restrict__ Wm1, const float* __restrict__ Wm2,
    const float* __restrict__ h0, const float* __restrict__ h1,
    float* __restrict__ s0, float* __restrict__ s1)
{
    const int lane = threadIdx.x & 63;
    const int e = blockIdx.x * 4 + (threadIdx.x >> 6);
    if (e >= E) return;
    const int src = eidx[e];
    const int dst = eidx[E + e];

    // hid[i] = silu((emb @ Wm1)[i] * inv_e); lanes 0..7 each compute one i.
    float part = 0.f;
    if (lane < 8) {
        #pragma unroll
        for (int j = 0; j < 8; ++j)
            part += eemb[(size_t)e * 8 + j] * Wm1[j * 8 + lane];
        part *= INV_E;
        part = silu(part);
    }
    float w1 = 0.f, w2 = 0.f, w3 = 0.f, w4 = 0.f;
    #pragma unroll
    for (int i = 0; i < 8; ++i) {
        float h = __shfl(part, i, 64);
        w1 += h * Wm2[i * 256 + lane];
        w2 += h * Wm2[i * 256 + 64 + lane];
        w3 += h * Wm2[i * 256 + 128 + lane];
        w4 += h * Wm2[i * 256 + 192 + lane];
    }
    w1 *= INV_E; w2 *= INV_E; w3 *= INV_E; w4 *= INV_E;

    const float g0  = h0[(size_t)src * 64 + lane];
    const float g1x = h1[(size_t)src * 192 + lane];
    const float g1y = h1[(size_t)src * 192 + 64 + lane];
    const float g1z = h1[(size_t)src * 192 + 128 + lane];

    const float a0 = eattr[(size_t)e * 4 + 0];
    const float ax = eattr[(size_t)e * 4 + 1];
    const float ay = eattr[(size_t)e * 4 + 2];
    const float az = eattr[(size_t)e * 4 + 3];

    const float m0a  = w1 * g0 * a0;
    const float dotv = g1x * ax + g1y * ay + g1z * az;
    const float m0b  = w4 * dotv * INV_SQRT3;

    float* s0p = &s0[(size_t)dst * 128];
    atomicAdd(s0p + lane,       m0a);
    atomicAdd(s0p + 64 + lane,  m0b);

    const float wg  = w2 * g0;   // m1_a channel factor
    const float w3a = w3 * a0;   // m1_b channel factor
    float* s1p = &s1[(size_t)dst * 384];
    // m1_a at k = lane (first 64 of k), per d plane
    atomicAdd(s1p + 0 * 128 + lane,      wg * ax);
    atomicAdd(s1p + 1 * 128 + lane,      wg * ay);
    atomicAdd(s1p + 2 * 128 + lane,      wg * az);
    // m1_b at k = 64 + lane
    atomicAdd(s1p + 0 * 128 + 64 + lane, w3a * g1x);
    atomicAdd(s1p + 1 * 128 + 64 + lane, w3a * g1y);
    atomicAdd(s1p + 2 * 128 + 64 + lane, w3a * g1z);
}

// ---------------------------------------------------------------------------
// Kernel 3: per-node post (lin2 + self-connection + gating + residual).
// 4 nodes per 320-thread block. Threads 0..127: t0 (128 outs);
// threads 128..319: t1 (192 outs, d = (tid-128)>>6, w = (tid-128)&63).
// Per-thread acc[4] amortizes each weight load over 4 nodes.
// ---------------------------------------------------------------------------
__global__ __launch_bounds__(320) void k_node_post(
    const float* __restrict__ x,
    const float* __restrict__ attrs,
    const float* __restrict__ s0g, const float* __restrict__ s1g,
    const float* __restrict__ W20, const float* __restrict__ W21,
    const float* __restrict__ Wsc0, const float* __restrict__ Wsc1,
    float* __restrict__ out)
{
    const int tid = threadIdx.x;
    const int n0 = blockIdx.x * 4;
    __shared__ float sh_x[4][256];
    __shared__ float sh_s0[4][128];
    __shared__ float sh_s1[4][384];     // [d][k] per node
    __shared__ float sh_xz[4][256];     // x0[u]*attr[z], idx u*4+z
    __shared__ float sh_xz1[4][3][256]; // x1[u][d]*attr[z], [d][u*4+z]
    __shared__ float sh_t0[4][128];
    __shared__ float sh_t1[4][192];     // [w*3+d]
    __shared__ float sh_at[4][4];

    for (int i = tid; i < 1024; i += 320) {
        int t = i >> 8, c = i & 255;
        sh_x[t][c] = x[(size_t)(n0 + t) * 256 + c];
    }
    for (int i = tid; i < 512; i += 320) {
        int t = i >> 7, c = i & 127;
        sh_s0[t][c] = s0g[(size_t)(n0 + t) * 128 + c] * INV_N;
    }
    for (int i = tid; i < 1536; i += 320) {
        int t = i / 384, c = i - t * 384;
        sh_s1[t][c] = s1g[(size_t)(n0 + t) * 384 + c] * INV_N;
    }
    if (tid < 16) sh_at[tid >> 2][tid & 3] = attrs[(size_t)(n0 + (tid >> 2)) * 4 + (tid & 3)];
    __syncthreads();

    for (int i = tid; i < 1024; i += 320) {
        int t = i >> 8, j = i & 255, u = j >> 2, z = j & 3;
        sh_xz[t][j] = sh_x[t][u] * sh_at[t][z];
    }
    for (int i = tid; i < 3072; i += 320) {
        int t = i / 768, r = i - t * 768;
        int d = r >> 8, j = r & 255, u = j >> 2, z = j & 3;
        sh_xz1[t][d][j] = sh_x[t][64 + u * 3 + d] * sh_at[t][z];
    }
    __syncthreads();

    if (tid < 128) {
        const int w = tid;
        float acc[4]  = {0.f, 0.f, 0.f, 0.f};
        float acc2[4] = {0.f, 0.f, 0.f, 0.f};
        for (int k = 0; k < 128; ++k) {
            float wv = W20[k * 128 + w];
            #pragma unroll
            for (int t = 0; t < 4; ++t) acc[t] += sh_s0[t][k] * wv;
        }
        for (int i = 0; i < 256; ++i) {
            float wv = Wsc0[i * 128 + w];
            #pragma unroll
            for (int t = 0; t < 4; ++t) acc2[t] += sh_xz[t][i] * wv;
        }
        #pragma unroll
        for (int t = 0; t < 4; ++t)
            sh_t0[t][w] = acc[t] * INV2 + acc2[t] * INV_SC;
    } else {
        const int i0 = tid - 128;
        const int d = i0 >> 6;
        const int w = i0 & 63;
        float acc[4]  = {0.f, 0.f, 0.f, 0.f};
        float acc2[4] = {0.f, 0.f, 0.f, 0.f};
        for (int k = 0; k < 128; ++k) {
            float wv = W21[k * 64 + w];
            #pragma unroll
            for (int t = 0; t < 4; ++t) acc[t] += sh_s1[t][d * 128 + k] * wv;
        }
        for (int j = 0; j < 256; ++j) {
            float wv = Wsc1[j * 64 + w];
            #pragma unroll
            for (int t = 0; t < 4; ++t) acc2[t] += sh_xz1[t][d][j] * wv;
        }
        #pragma unroll
        for (int t = 0; t < 4; ++t)
            sh_t1[t][w * 3 + d] = acc[t] * INV2 + acc2[t] * INV_SC;
    }
    __syncthreads();

    for (int i = tid; i < 1024; i += 320) {
        int t = i >> 8, c = i & 255;
        float xv = sh_x[t][c];
        float o;
        if (c < 64) {
            o = xv + silu(sh_t0[t][c]);
        } else {
            int r = c - 64;
            int w = r / 3;
            o = xv + silu(sh_t0[t][64 + w]) * sh_t1[t][r];
        }
        out[(size_t)(n0 + t) * 256 + c] = o;
    }
}

extern "C" void kernel_launch(void* const* d_in, const int* in_sizes, int n_in,
                              void* d_out, int out_size, void* d_ws, size_t ws_size,
                              hipStream_t stream) {
    const float* node_feats = (const float*)d_in[0];
    const float* node_attrs = (const float*)d_in[1];
    const float* edge_attrs = (const float*)d_in[2];
    const float* edge_emb   = (const float*)d_in[3];
    const float* W_lin1_0   = (const float*)d_in[4];
    const float* W_lin1_1   = (const float*)d_in[5];
    const float* W_mlp1     = (const float*)d_in[6];
    const float* W_mlp2     = (const float*)d_in[7];
    const float* W_lin2_0   = (const float*)d_in[8];
    const float* W_lin2_1   = (const float*)d_in[9];
    const float* W_sc0      = (const float*)d_in[10];
    const float* W_sc1      = (const float*)d_in[11];
    const int*   edge_index = (const int*)d_in[12];
    float* out = (float*)d_out;

    float* ws = (float*)d_ws;
    float* h0 = ws;                      // N*64
    float* h1 = ws + (size_t)N * 64;     // N*192, layout [n][d][64]
    float* s0 = ws + (size_t)N * 256;    // N*128
    float* s1 = ws + (size_t)N * 384;    // N*384, layout [n][d][128]

    // zero the scatter accumulators (ws is poisoned before every launch)
    hipMemsetAsync(s0, 0, (size_t)N * 512 * sizeof(float), stream);

    k_node_pre<<<N / 4, 256, 0, stream>>>(node_feats, W_lin1_0, W_lin1_1, h0, h1);
    k_edge<<<E / 4, 256, 0, stream>>>(edge_index, edge_attrs, edge_emb,
                                      W_mlp1, W_mlp2, h0, h1, s0, s1);
    k_node_post<<<N / 4, 320, 0, stream>>>(node_feats, node_attrs, s0, s1,
                                           W_lin2_0, W_lin2_1, W_sc0, W_sc1, out);
}

// Round 2
// 395.731 us; speedup vs baseline: 1.3823x; 1.3823x over previous
//
#include <hip/hip_runtime.h>
#include <hip/hip_bf16.h>
#include <math.h>

#define N 20000
#define E 160000
#define MUL 64
#define EDIM 8
#define NZ 4

#define INV_SQRT_MUL 0.125f          // 1/sqrt(64)
#define INV_E 0.35355339059327373f   // 1/sqrt(8)
#define INV_N 0.35355339059327373f   // 1/sqrt(8)
#define INV2 0.08838834764831845f    // 1/sqrt(128)
#define INV_SC 0.0625f               // 1/sqrt(256)
#define INV_SQRT3 0.5773502691896258f

__device__ __forceinline__ float silu(float v) {
    return v / (1.0f + __expf(-v));
}

// ---------------------------------------------------------------------------
// Kernel 1: per-node linear (lin1).  4 nodes per 256-thread block.
// h0[n][v]; h1 stored [n][d][v] (d-major, coalesced)
// ---------------------------------------------------------------------------
__global__ __launch_bounds__(256) void k_node_pre(
    const float* __restrict__ x,
    const float* __restrict__ W0, const float* __restrict__ W1,
    float* __restrict__ h0, float* __restrict__ h1)
{
    const int tid = threadIdx.x;
    const int n0 = blockIdx.x * 4;
    __shared__ float xrow[4][256];
    for (int i = tid; i < 1024; i += 256) {
        int t = i >> 8, c = i & 255;
        xrow[t][c] = x[(size_t)(n0 + t) * 256 + c];
    }
    __syncthreads();
    const int v = tid & 63;
    const int part = tid >> 6;
    float acc[4] = {0.f, 0.f, 0.f, 0.f};
    if (part == 0) {
        for (int u = 0; u < 64; ++u) {
            float wv = W0[u * 64 + v];
            #pragma unroll
            for (int t = 0; t < 4; ++t) acc[t] += xrow[t][u] * wv;
        }
        #pragma unroll
        for (int t = 0; t < 4; ++t)
            h0[(size_t)(n0 + t) * 64 + v] = acc[t] * INV_SQRT_MUL;
    } else {
        const int d = part - 1;
        for (int u = 0; u < 64; ++u) {
            float wv = W1[u * 64 + v];
            #pragma unroll
            for (int t = 0; t < 4; ++t) acc[t] += xrow[t][64 + u * 3 + d] * wv;
        }
        #pragma unroll
        for (int t = 0; t < 4; ++t)
            h1[(size_t)(n0 + t) * 192 + d * 64 + v] = acc[t] * INV_SQRT_MUL;
    }
}

// ---------------------------------------------------------------------------
// CSR build: histogram -> scan -> scatter permutation
// ---------------------------------------------------------------------------
__global__ __launch_bounds__(256) void k_hist(
    const int* __restrict__ eidx, int* __restrict__ counts)
{
    int e = blockIdx.x * 256 + threadIdx.x;
    if (e < E) atomicAdd(&counts[eidx[E + e]], 1);
}

// single block, 1024 threads; cursor may alias counts (read-before-write per idx)
__global__ __launch_bounds__(1024) void k_scan(
    const int* __restrict__ counts, int* __restrict__ offsets,
    int* __restrict__ cursor)
{
    __shared__ int part[1024];
    const int tid = threadIdx.x;
    const int CH = 20;                 // 1024*20 >= N
    const int base = tid * CH;
    int s = 0;
    for (int i = 0; i < CH; ++i) {
        int idx = base + i;
        if (idx < N) s += counts[idx];
    }
    part[tid] = s;
    __syncthreads();
    for (int off = 1; off < 1024; off <<= 1) {
        int v = (tid >= off) ? part[tid - off] : 0;
        __syncthreads();
        part[tid] += v;
        __syncthreads();
    }
    int run = (tid > 0) ? part[tid - 1] : 0;
    for (int i = 0; i < CH; ++i) {
        int idx = base + i;
        if (idx < N) {
            int c = counts[idx];
            offsets[idx] = run;
            cursor[idx] = run;
            run += c;
        }
    }
    if (tid == 0) offsets[N] = part[1023];
}

__global__ __launch_bounds__(256) void k_scatter(
    const int* __restrict__ eidx, int* __restrict__ cursor,
    int* __restrict__ perm)
{
    int e = blockIdx.x * 256 + threadIdx.x;
    if (e < E) {
        int pos = atomicAdd(&cursor[eidx[E + e]], 1);
        perm[pos] = e;
    }
}

// ---------------------------------------------------------------------------
// Kernel 2: gather — one wave per dst node; walks its CSR segment, computes
// the edge MLP in-wave, accumulates s0/s1 in registers, single coalesced store.
// s0 layout [n][128]; s1 layout [n][d][128].
// ---------------------------------------------------------------------------
__global__ __launch_bounds__(256) void k_gather(
    const int* __restrict__ perm, const int* __restrict__ offsets,
    const int* __restrict__ eidx,
    const float* __restrict__ eattr, const float* __restrict__ eemb,
    const float* __restrict__ Wm1, const float* __restrict__ Wm2,
    const float* __restrict__ h0, const float* __restrict__ h1,
    float* __restrict__ s0, float* __restrict__ s1)
{
    const int lane = threadIdx.x & 63;
    const int n = blockIdx.x * 4 + (threadIdx.x >> 6);
    const int beg = offsets[n];
    const int end = offsets[n + 1];

    float acc0a = 0.f, acc0b = 0.f;
    float a1a[3] = {0.f, 0.f, 0.f};   // m1_a per d
    float a1b[3] = {0.f, 0.f, 0.f};   // m1_b per d

    for (int i = beg; i < end; ++i) {
        const int e = perm[i];
        const int src = eidx[e];

        // edge MLP: hid[i]=silu((emb@Wm1)[i]*inv_e) on lanes 0..7
        float embv = (lane < 8) ? eemb[(size_t)e * 8 + lane] : 0.f;
        float hid = 0.f;
        #pragma unroll
        for (int j = 0; j < 8; ++j)
            hid += __shfl(embv, j, 64) * Wm1[j * 8 + (lane & 7)];
        hid = silu(hid * INV_E);

        float w1 = 0.f, w2 = 0.f, w3 = 0.f, w4 = 0.f;
        #pragma unroll
        for (int k = 0; k < 8; ++k) {
            float h = __shfl(hid, k, 64);
            w1 += h * Wm2[k * 256 + lane];
            w2 += h * Wm2[k * 256 + 64 + lane];
            w3 += h * Wm2[k * 256 + 128 + lane];
            w4 += h * Wm2[k * 256 + 192 + lane];
        }
        w1 *= INV_E; w2 *= INV_E; w3 *= INV_E; w4 *= INV_E;

        const float g0  = h0[(size_t)src * 64 + lane];
        const float g1x = h1[(size_t)src * 192 + lane];
        const float g1y = h1[(size_t)src * 192 + 64 + lane];
        const float g1z = h1[(size_t)src * 192 + 128 + lane];

        const float a0 = eattr[(size_t)e * 4 + 0];
        const float ax = eattr[(size_t)e * 4 + 1];
        const float ay = eattr[(size_t)e * 4 + 2];
        const float az = eattr[(size_t)e * 4 + 3];

        acc0a += w1 * g0 * a0;
        const float dotv = g1x * ax + g1y * ay + g1z * az;
        acc0b += w4 * dotv * INV_SQRT3;

        const float wg  = w2 * g0;
        const float w3a = w3 * a0;
        a1a[0] += wg * ax;  a1a[1] += wg * ay;  a1a[2] += wg * az;
        a1b[0] += w3a * g1x; a1b[1] += w3a * g1y; a1b[2] += w3a * g1z;
    }

    float* s0p = &s0[(size_t)n * 128];
    s0p[lane] = acc0a;
    s0p[64 + lane] = acc0b;
    float* s1p = &s1[(size_t)n * 384];
    #pragma unroll
    for (int d = 0; d < 3; ++d) {
        s1p[d * 128 + lane] = a1a[d];
        s1p[d * 128 + 64 + lane] = a1b[d];
    }
}

// ---------------------------------------------------------------------------
// Kernel 3: per-node post (lin2 + self-connection + gating + residual).
// ---------------------------------------------------------------------------
__global__ __launch_bounds__(320) void k_node_post(
    const float* __restrict__ x,
    const float* __restrict__ attrs,
    const float* __restrict__ s0g, const float* __restrict__ s1g,
    const float* __restrict__ W20, const float* __restrict__ W21,
    const float* __restrict__ Wsc0, const float* __restrict__ Wsc1,
    float* __restrict__ out)
{
    const int tid = threadIdx.x;
    const int n0 = blockIdx.x * 4;
    __shared__ float sh_x[4][256];
    __shared__ float sh_s0[4][128];
    __shared__ float sh_s1[4][384];     // [d][k] per node
    __shared__ float sh_xz[4][256];     // x0[u]*attr[z], idx u*4+z
    __shared__ float sh_xz1[4][3][256]; // x1[u][d]*attr[z], [d][u*4+z]
    __shared__ float sh_t0[4][128];
    __shared__ float sh_t1[4][192];     // [w*3+d]
    __shared__ float sh_at[4][4];

    for (int i = tid; i < 1024; i += 320) {
        int t = i >> 8, c = i & 255;
        sh_x[t][c] = x[(size_t)(n0 + t) * 256 + c];
    }
    for (int i = tid; i < 512; i += 320) {
        int t = i >> 7, c = i & 127;
        sh_s0[t][c] = s0g[(size_t)(n0 + t) * 128 + c] * INV_N;
    }
    for (int i = tid; i < 1536; i += 320) {
        int t = i / 384, c = i - t * 384;
        sh_s1[t][c] = s1g[(size_t)(n0 + t) * 384 + c] * INV_N;
    }
    if (tid < 16) sh_at[tid >> 2][tid & 3] = attrs[(size_t)(n0 + (tid >> 2)) * 4 + (tid & 3)];
    __syncthreads();

    for (int i = tid; i < 1024; i += 320) {
        int t = i >> 8, j = i & 255, u = j >> 2, z = j & 3;
        sh_xz[t][j] = sh_x[t][u] * sh_at[t][z];
    }
    for (int i = tid; i < 3072; i += 320) {
        int t = i / 768, r = i - t * 768;
        int d = r >> 8, j = r & 255, u = j >> 2, z = j & 3;
        sh_xz1[t][d][j] = sh_x[t][64 + u * 3 + d] * sh_at[t][z];
    }
    __syncthreads();

    if (tid < 128) {
        const int w = tid;
        float acc[4]  = {0.f, 0.f, 0.f, 0.f};
        float acc2[4] = {0.f, 0.f, 0.f, 0.f};
        for (int k = 0; k < 128; ++k) {
            float wv = W20[k * 128 + w];
            #pragma unroll
            for (int t = 0; t < 4; ++t) acc[t] += sh_s0[t][k] * wv;
        }
        for (int i = 0; i < 256; ++i) {
            float wv = Wsc0[i * 128 + w];
            #pragma unroll
            for (int t = 0; t < 4; ++t) acc2[t] += sh_xz[t][i] * wv;
        }
        #pragma unroll
        for (int t = 0; t < 4; ++t)
            sh_t0[t][w] = acc[t] * INV2 + acc2[t] * INV_SC;
    } else {
        const int i0 = tid - 128;
        const int d = i0 >> 6;
        const int w = i0 & 63;
        float acc[4]  = {0.f, 0.f, 0.f, 0.f};
        float acc2[4] = {0.f, 0.f, 0.f, 0.f};
        for (int k = 0; k < 128; ++k) {
            float wv = W21[k * 64 + w];
            #pragma unroll
            for (int t = 0; t < 4; ++t) acc[t] += sh_s1[t][d * 128 + k] * wv;
        }
        for (int j = 0; j < 256; ++j) {
            float wv = Wsc1[j * 64 + w];
            #pragma unroll
            for (int t = 0; t < 4; ++t) acc2[t] += sh_xz1[t][d][j] * wv;
        }
        #pragma unroll
        for (int t = 0; t < 4; ++t)
            sh_t1[t][w * 3 + d] = acc[t] * INV2 + acc2[t] * INV_SC;
    }
    __syncthreads();

    for (int i = tid; i < 1024; i += 320) {
        int t = i >> 8, c = i & 255;
        float xv = sh_x[t][c];
        float o;
        if (c < 64) {
            o = xv + silu(sh_t0[t][c]);
        } else {
            int r = c - 64;
            int w = r / 3;
            o = xv + silu(sh_t0[t][64 + w]) * sh_t1[t][r];
        }
        out[(size_t)(n0 + t) * 256 + c] = o;
    }
}

extern "C" void kernel_launch(void* const* d_in, const int* in_sizes, int n_in,
                              void* d_out, int out_size, void* d_ws, size_t ws_size,
                              hipStream_t stream) {
    const float* node_feats = (const float*)d_in[0];
    const float* node_attrs = (const float*)d_in[1];
    const float* edge_attrs = (const float*)d_in[2];
    const float* edge_emb   = (const float*)d_in[3];
    const float* W_lin1_0   = (const float*)d_in[4];
    const float* W_lin1_1   = (const float*)d_in[5];
    const float* W_mlp1     = (const float*)d_in[6];
    const float* W_mlp2     = (const float*)d_in[7];
    const float* W_lin2_0   = (const float*)d_in[8];
    const float* W_lin2_1   = (const float*)d_in[9];
    const float* W_sc0      = (const float*)d_in[10];
    const float* W_sc1      = (const float*)d_in[11];
    const int*   edge_index = (const int*)d_in[12];
    float* out = (float*)d_out;

    float* ws = (float*)d_ws;
    float* h0 = ws;                      // N*64
    float* h1 = ws + (size_t)N * 64;     // N*192, [n][d][64]
    float* s0 = ws + (size_t)N * 256;    // N*128
    float* s1 = ws + (size_t)N * 384;    // N*384, [n][d][128]
    int*   counts  = (int*)(ws + (size_t)N * 768);  // N (also reused as cursor)
    int*   offsets = counts + N;                    // N+1
    int*   perm    = offsets + (N + 1);             // E

    hipMemsetAsync(counts, 0, N * sizeof(int), stream);

    k_node_pre<<<N / 4, 256, 0, stream>>>(node_feats, W_lin1_0, W_lin1_1, h0, h1);
    k_hist<<<(E + 255) / 256, 256, 0, stream>>>(edge_index, counts);
    k_scan<<<1, 1024, 0, stream>>>(counts, offsets, counts);
    k_scatter<<<(E + 255) / 256, 256, 0, stream>>>(edge_index, counts, perm);
    k_gather<<<N / 4, 256, 0, stream>>>(perm, offsets, edge_index,
                                        edge_attrs, edge_emb, W_mlp1, W_mlp2,
                                        h0, h1, s0, s1);
    k_node_post<<<N / 4, 320, 0, stream>>>(node_feats, node_attrs, s0, s1,
                                           W_lin2_0, W_lin2_1, W_sc0, W_sc1, out);
}

// Round 3
// 320.755 us; speedup vs baseline: 1.7054x; 1.2337x over previous
//
#include <hip/hip_runtime.h>
#include <hip/hip_bf16.h>
#include <math.h>

#define N 20000
#define E 160000
#define MUL 64
#define EDIM 8
#define NZ 4

#define INV_SQRT_MUL 0.125f          // 1/sqrt(64)
#define INV_E 0.35355339059327373f   // 1/sqrt(8)
#define INV_N 0.35355339059327373f   // 1/sqrt(8)
#define INV2 0.08838834764831845f    // 1/sqrt(128)
#define INV_SC 0.0625f               // 1/sqrt(256)
#define INV_SQRT3 0.5773502691896258f

typedef unsigned short u16;
typedef short bf16x8 __attribute__((ext_vector_type(8)));
typedef float f32x4 __attribute__((ext_vector_type(4)));

__device__ __forceinline__ float silu(float v) {
    return v / (1.0f + __expf(-v));
}

// float -> bf16 bits, round-to-nearest-even
__device__ __forceinline__ u16 f2bf(float f) {
    union { float f; unsigned int u; } v; v.f = f;
    unsigned int r = (v.u + 0x7FFFu + ((v.u >> 16) & 1u)) >> 16;
    return (u16)r;
}

// ---------------------------------------------------------------------------
// Kernel 1: per-node linear (lin1).  4 nodes per 256-thread block.
// h0[n][v]; h1 stored [n][d][v]
// ---------------------------------------------------------------------------
__global__ __launch_bounds__(256) void k_node_pre(
    const float* __restrict__ x,
    const float* __restrict__ W0, const float* __restrict__ W1,
    float* __restrict__ h0, float* __restrict__ h1)
{
    const int tid = threadIdx.x;
    const int n0 = blockIdx.x * 4;
    __shared__ float xrow[4][256];
    for (int i = tid; i < 1024; i += 256) {
        int t = i >> 8, c = i & 255;
        xrow[t][c] = x[(size_t)(n0 + t) * 256 + c];
    }
    __syncthreads();
    const int v = tid & 63;
    const int part = tid >> 6;
    float acc[4] = {0.f, 0.f, 0.f, 0.f};
    if (part == 0) {
        for (int u = 0; u < 64; ++u) {
            float wv = W0[u * 64 + v];
            #pragma unroll
            for (int t = 0; t < 4; ++t) acc[t] += xrow[t][u] * wv;
        }
        #pragma unroll
        for (int t = 0; t < 4; ++t)
            h0[(size_t)(n0 + t) * 64 + v] = acc[t] * INV_SQRT_MUL;
    } else {
        const int d = part - 1;
        for (int u = 0; u < 64; ++u) {
            float wv = W1[u * 64 + v];
            #pragma unroll
            for (int t = 0; t < 4; ++t) acc[t] += xrow[t][64 + u * 3 + d] * wv;
        }
        #pragma unroll
        for (int t = 0; t < 4; ++t)
            h1[(size_t)(n0 + t) * 192 + d * 64 + v] = acc[t] * INV_SQRT_MUL;
    }
}

// ---------------------------------------------------------------------------
// CSR build: histogram -> scan -> scatter permutation
// ---------------------------------------------------------------------------
__global__ __launch_bounds__(256) void k_hist(
    const int* __restrict__ eidx, int* __restrict__ counts)
{
    int e = blockIdx.x * 256 + threadIdx.x;
    if (e < E) atomicAdd(&counts[eidx[E + e]], 1);
}

__global__ __launch_bounds__(1024) void k_scan(
    const int* __restrict__ counts, int* __restrict__ offsets,
    int* __restrict__ cursor)
{
    __shared__ int part[1024];
    const int tid = threadIdx.x;
    const int CH = 20;
    const int base = tid * CH;
    int s = 0;
    for (int i = 0; i < CH; ++i) {
        int idx = base + i;
        if (idx < N) s += counts[idx];
    }
    part[tid] = s;
    __syncthreads();
    for (int off = 1; off < 1024; off <<= 1) {
        int v = (tid >= off) ? part[tid - off] : 0;
        __syncthreads();
        part[tid] += v;
        __syncthreads();
    }
    int run = (tid > 0) ? part[tid - 1] : 0;
    for (int i = 0; i < CH; ++i) {
        int idx = base + i;
        if (idx < N) {
            int c = counts[idx];
            offsets[idx] = run;
            cursor[idx] = run;
            run += c;
        }
    }
    if (tid == 0) offsets[N] = part[1023];
}

__global__ __launch_bounds__(256) void k_scatter(
    const int* __restrict__ eidx, int* __restrict__ cursor,
    int* __restrict__ perm)
{
    int e = blockIdx.x * 256 + threadIdx.x;
    if (e < E) {
        int pos = atomicAdd(&cursor[eidx[E + e]], 1);
        perm[pos] = e;
    }
}

// ---------------------------------------------------------------------------
// Weight conversion: Bt1[128][384] (k<128: W20[k][w], else Wsc0[k-128][w])
//                    Bt2[64][384]  (k<128: W21[k][w], else Wsc1[k-128][w])
// ---------------------------------------------------------------------------
__global__ __launch_bounds__(256) void k_wconv(
    const float* __restrict__ W20, const float* __restrict__ Wsc0,
    const float* __restrict__ W21, const float* __restrict__ Wsc1,
    u16* __restrict__ Bt1, u16* __restrict__ Bt2)
{
    int i = blockIdx.x * 256 + threadIdx.x;
    if (i < 128 * 384) {
        int w = i / 384, k = i % 384;
        float v = (k < 128) ? W20[k * 128 + w] : Wsc0[(k - 128) * 128 + w];
        Bt1[i] = f2bf(v);
    } else {
        int j = i - 128 * 384;
        if (j < 64 * 384) {
            int w = j / 384, k = j % 384;
            float v = (k < 128) ? W21[k * 64 + w] : Wsc1[(k - 128) * 64 + w];
            Bt2[j] = f2bf(v);
        }
    }
}

// ---------------------------------------------------------------------------
// Fill xz columns (128..383) of A1 / A2.  One node per 256-thread block.
// A1[n][128 + u*4+z] = x0[u]*attr[z]*INV_SC
// A2[(n*3+d)][128 + u*4+z] = x1[u][d]*attr[z]*INV_SC
// ---------------------------------------------------------------------------
__global__ __launch_bounds__(256) void k_prep_xz(
    const float* __restrict__ x, const float* __restrict__ attrs,
    u16* __restrict__ A1, u16* __restrict__ A2)
{
    const int n = blockIdx.x;
    const int tid = threadIdx.x;
    __shared__ float xr[256];
    xr[tid] = x[(size_t)n * 256 + tid];
    __syncthreads();
    const float at = attrs[(size_t)n * 4 + (tid & 3)] * INV_SC;
    const int u = tid >> 2;
    A1[(size_t)n * 384 + 128 + tid] = f2bf(xr[u] * at);
    #pragma unroll
    for (int d = 0; d < 3; ++d)
        A2[((size_t)n * 3 + d) * 384 + 128 + tid] = f2bf(xr[64 + u * 3 + d] * at);
}

// ---------------------------------------------------------------------------
// Gather: one wave per dst node; edge MLP in-wave; accumulate in registers;
// store bf16 directly into A1 cols 0..127 and A2 cols 0..127 (scales folded).
// ---------------------------------------------------------------------------
__global__ __launch_bounds__(256) void k_gather(
    const int* __restrict__ perm, const int* __restrict__ offsets,
    const int* __restrict__ eidx,
    const float* __restrict__ eattr, const float* __restrict__ eemb,
    const float* __restrict__ Wm1, const float* __restrict__ Wm2,
    const float* __restrict__ h0, const float* __restrict__ h1,
    u16* __restrict__ A1, u16* __restrict__ A2)
{
    const int lane = threadIdx.x & 63;
    const int n = blockIdx.x * 4 + (threadIdx.x >> 6);
    const int beg = offsets[n];
    const int end = offsets[n + 1];

    float acc0a = 0.f, acc0b = 0.f;
    float a1a[3] = {0.f, 0.f, 0.f};
    float a1b[3] = {0.f, 0.f, 0.f};

    for (int i = beg; i < end; ++i) {
        const int e = perm[i];
        const int src = eidx[e];

        float embv = (lane < 8) ? eemb[(size_t)e * 8 + lane] : 0.f;
        float hid = 0.f;
        #pragma unroll
        for (int j = 0; j < 8; ++j)
            hid += __shfl(embv, j, 64) * Wm1[j * 8 + (lane & 7)];
        hid = silu(hid * INV_E);

        float w1 = 0.f, w2 = 0.f, w3 = 0.f, w4 = 0.f;
        #pragma unroll
        for (int k = 0; k < 8; ++k) {
            float h = __shfl(hid, k, 64);
            w1 += h * Wm2[k * 256 + lane];
            w2 += h * Wm2[k * 256 + 64 + lane];
            w3 += h * Wm2[k * 256 + 128 + lane];
            w4 += h * Wm2[k * 256 + 192 + lane];
        }
        w1 *= INV_E; w2 *= INV_E; w3 *= INV_E; w4 *= INV_E;

        const float g0  = h0[(size_t)src * 64 + lane];
        const float g1x = h1[(size_t)src * 192 + lane];
        const float g1y = h1[(size_t)src * 192 + 64 + lane];
        const float g1z = h1[(size_t)src * 192 + 128 + lane];

        const float a0 = eattr[(size_t)e * 4 + 0];
        const float ax = eattr[(size_t)e * 4 + 1];
        const float ay = eattr[(size_t)e * 4 + 2];
        const float az = eattr[(size_t)e * 4 + 3];

        acc0a += w1 * g0 * a0;
        const float dotv = g1x * ax + g1y * ay + g1z * az;
        acc0b += w4 * dotv * INV_SQRT3;

        const float wg  = w2 * g0;
        const float w3a = w3 * a0;
        a1a[0] += wg * ax;  a1a[1] += wg * ay;  a1a[2] += wg * az;
        a1b[0] += w3a * g1x; a1b[1] += w3a * g1y; a1b[2] += w3a * g1z;
    }

    const float sc = INV_N * INV2;   // fold segment-mean + lin2 scale into A
    u16* a1p = &A1[(size_t)n * 384];
    a1p[lane]      = f2bf(acc0a * sc);
    a1p[64 + lane] = f2bf(acc0b * sc);
    #pragma unroll
    for (int d = 0; d < 3; ++d) {
        u16* a2p = &A2[((size_t)n * 3 + d) * 384];
        a2p[lane]      = f2bf(a1a[d] * sc);
        a2p[64 + lane] = f2bf(a1b[d] * sc);
    }
}

// ---------------------------------------------------------------------------
// bf16 MFMA GEMM: C(M x NCOLS) = A(M x 384) @ Bt^T, Bt is [NCOLS][384].
// Block 256 = 4 waves; block tile 64 rows; wave tile 16 rows x NCOLS.
// ---------------------------------------------------------------------------
template<int NCOLS>
__global__ __launch_bounds__(256) void k_gemm(
    const u16* __restrict__ A, const u16* __restrict__ Bt,
    float* __restrict__ C, int M)
{
    constexpr int NT = NCOLS / 16;
    const int lane = threadIdx.x & 63;
    const int wave = threadIdx.x >> 6;
    const int quad = lane >> 4;
    const int l16 = lane & 15;
    const int row0 = blockIdx.x * 64 + wave * 16 + l16;

    f32x4 acc[NT] = {};
    #pragma unroll
    for (int k0 = 0; k0 < 384; k0 += 32) {
        bf16x8 a;
        if (row0 < M)
            a = *(const bf16x8*)(A + (size_t)row0 * 384 + k0 + quad * 8);
        else
            a = (bf16x8){0, 0, 0, 0, 0, 0, 0, 0};
        #pragma unroll
        for (int t = 0; t < NT; ++t) {
            bf16x8 b = *(const bf16x8*)(Bt + (size_t)(t * 16 + l16) * 384 + k0 + quad * 8);
            acc[t] = __builtin_amdgcn_mfma_f32_16x16x32_bf16(a, b, acc[t], 0, 0, 0);
        }
    }
    const int rowg = blockIdx.x * 64 + wave * 16 + quad * 4;
    #pragma unroll
    for (int t = 0; t < NT; ++t) {
        #pragma unroll
        for (int r = 0; r < 4; ++r) {
            int rr = rowg + r;
            if (rr < M) C[(size_t)rr * NCOLS + t * 16 + l16] = acc[t][r];
        }
    }
}

// ---------------------------------------------------------------------------
// Epilogue: out[n][c] = x + silu/gate.  One node per 256-thread block.
// ---------------------------------------------------------------------------
__global__ __launch_bounds__(256) void k_epilogue(
    const float* __restrict__ x,
    const float* __restrict__ t0, const float* __restrict__ t1,
    float* __restrict__ out)
{
    const int n = blockIdx.x;
    const int c = threadIdx.x;
    const float xv = x[(size_t)n * 256 + c];
    float o;
    if (c < 64) {
        o = xv + silu(t0[(size_t)n * 128 + c]);
    } else {
        int r = c - 64;
        int w = r / 3;
        int d = r - w * 3;
        o = xv + silu(t0[(size_t)n * 128 + 64 + w]) * t1[((size_t)n * 3 + d) * 64 + w];
    }
    out[(size_t)n * 256 + c] = o;
}

extern "C" void kernel_launch(void* const* d_in, const int* in_sizes, int n_in,
                              void* d_out, int out_size, void* d_ws, size_t ws_size,
                              hipStream_t stream) {
    const float* node_feats = (const float*)d_in[0];
    const float* node_attrs = (const float*)d_in[1];
    const float* edge_attrs = (const float*)d_in[2];
    const float* edge_emb   = (const float*)d_in[3];
    const float* W_lin1_0   = (const float*)d_in[4];
    const float* W_lin1_1   = (const float*)d_in[5];
    const float* W_mlp1     = (const float*)d_in[6];
    const float* W_mlp2     = (const float*)d_in[7];
    const float* W_lin2_0   = (const float*)d_in[8];
    const float* W_lin2_1   = (const float*)d_in[9];
    const float* W_sc0      = (const float*)d_in[10];
    const float* W_sc1      = (const float*)d_in[11];
    const int*   edge_index = (const int*)d_in[12];
    float* out = (float*)d_out;

    // Workspace layout (R = N*320 floats, h0/h1 later overlaid by t0/t1):
    float* R  = (float*)d_ws;
    float* h0 = R;                        // N*64   (pre-gather)
    float* h1 = R + (size_t)N * 64;       // N*192  (pre-gather)
    float* t0 = R;                        // N*128  (post-gather, overlays h0+)
    float* t1 = R + (size_t)N * 128;      // N*192  (post-gather)
    u16* A1  = (u16*)(R + (size_t)N * 320);      // N*384 bf16
    u16* A2  = A1 + (size_t)N * 384;             // N*1152 bf16
    u16* Bt1 = A2 + (size_t)N * 1152;            // 128*384
    u16* Bt2 = Bt1 + 128 * 384;                  // 64*384
    int* counts  = (int*)(Bt2 + 64 * 384);       // N (reused as cursor)
    int* offsets = counts + N;                   // N+1
    int* perm    = offsets + (N + 1);            // E

    hipMemsetAsync(counts, 0, N * sizeof(int), stream);

    k_node_pre<<<N / 4, 256, 0, stream>>>(node_feats, W_lin1_0, W_lin1_1, h0, h1);
    k_hist<<<(E + 255) / 256, 256, 0, stream>>>(edge_index, counts);
    k_scan<<<1, 1024, 0, stream>>>(counts, offsets, counts);
    k_scatter<<<(E + 255) / 256, 256, 0, stream>>>(edge_index, counts, perm);
    k_wconv<<<(128 * 384 + 64 * 384 + 255) / 256, 256, 0, stream>>>(
        W_lin2_0, W_sc0, W_lin2_1, W_sc1, Bt1, Bt2);
    k_prep_xz<<<N, 256, 0, stream>>>(node_feats, node_attrs, A1, A2);
    k_gather<<<N / 4, 256, 0, stream>>>(perm, offsets, edge_index,
                                        edge_attrs, edge_emb, W_mlp1, W_mlp2,
                                        h0, h1, A1, A2);
    k_gemm<128><<<(N + 63) / 64, 256, 0, stream>>>(A1, Bt1, t0, N);
    k_gemm<64><<<(3 * N + 63) / 64, 256, 0, stream>>>(A2, Bt2, t1, 3 * N);
    k_epilogue<<<N, 256, 0, stream>>>(node_feats, t0, t1, out);
}

// Round 4
// 310.743 us; speedup vs baseline: 1.7604x; 1.0322x over previous
//
#include <hip/hip_runtime.h>
#include <hip/hip_bf16.h>
#include <math.h>

#define N 20000
#define E 160000
#define MUL 64
#define EDIM 8
#define NZ 4

#define INV_SQRT_MUL 0.125f          // 1/sqrt(64)
#define INV_E 0.35355339059327373f   // 1/sqrt(8)
#define INV_N 0.35355339059327373f   // 1/sqrt(8)
#define INV2 0.08838834764831845f    // 1/sqrt(128)
#define INV_SC 0.0625f               // 1/sqrt(256)
#define INV_SQRT3 0.5773502691896258f

typedef unsigned short u16;
typedef short bf16x8 __attribute__((ext_vector_type(8)));
typedef float f32x4 __attribute__((ext_vector_type(4)));

__device__ __forceinline__ float silu(float v) {
    return v / (1.0f + __expf(-v));
}

__device__ __forceinline__ u16 f2bf(float f) {
    union { float f; unsigned int u; } v; v.f = f;
    unsigned int r = (v.u + 0x7FFFu + ((v.u >> 16) & 1u)) >> 16;
    return (u16)r;
}

// ---------------------------------------------------------------------------
// Kernel 1: per-node linear (lin1) -> AoS layout hc[n][u][4] = (g0,g1x,g1y,g1z)
// ---------------------------------------------------------------------------
__global__ __launch_bounds__(256) void k_node_pre(
    const float* __restrict__ x,
    const float* __restrict__ W0, const float* __restrict__ W1,
    float* __restrict__ hc)
{
    const int tid = threadIdx.x;
    const int n0 = blockIdx.x * 4;
    __shared__ float xrow[4][256];
    for (int i = tid; i < 1024; i += 256) {
        int t = i >> 8, c = i & 255;
        xrow[t][c] = x[(size_t)(n0 + t) * 256 + c];
    }
    __syncthreads();
    const int v = tid & 63;
    const int part = tid >> 6;
    float acc[4] = {0.f, 0.f, 0.f, 0.f};
    if (part == 0) {
        for (int u = 0; u < 64; ++u) {
            float wv = W0[u * 64 + v];
            #pragma unroll
            for (int t = 0; t < 4; ++t) acc[t] += xrow[t][u] * wv;
        }
        #pragma unroll
        for (int t = 0; t < 4; ++t)
            hc[(size_t)(n0 + t) * 256 + v * 4 + 0] = acc[t] * INV_SQRT_MUL;
    } else {
        const int d = part - 1;
        for (int u = 0; u < 64; ++u) {
            float wv = W1[u * 64 + v];
            #pragma unroll
            for (int t = 0; t < 4; ++t) acc[t] += xrow[t][64 + u * 3 + d] * wv;
        }
        #pragma unroll
        for (int t = 0; t < 4; ++t)
            hc[(size_t)(n0 + t) * 256 + v * 4 + 1 + d] = acc[t] * INV_SQRT_MUL;
    }
}

// ---------------------------------------------------------------------------
// Dense edge-MLP hidden layer: hid[e][k] = silu(inv_e * (emb[e] @ Wm1)[k])
// ---------------------------------------------------------------------------
__global__ __launch_bounds__(256) void k_hid(
    const float* __restrict__ eemb, const float* __restrict__ Wm1,
    float* __restrict__ hid)
{
    int i = blockIdx.x * 256 + threadIdx.x;
    if (i < E * 8) {
        int e = i >> 3, k = i & 7;
        float s = 0.f;
        #pragma unroll
        for (int j = 0; j < 8; ++j)
            s += eemb[(size_t)e * 8 + j] * Wm1[j * 8 + k];
        hid[i] = silu(s * INV_E);
    }
}

// ---------------------------------------------------------------------------
// CSR build: histogram -> scan -> scatter permutation
// ---------------------------------------------------------------------------
__global__ __launch_bounds__(256) void k_hist(
    const int* __restrict__ eidx, int* __restrict__ counts)
{
    int e = blockIdx.x * 256 + threadIdx.x;
    if (e < E) atomicAdd(&counts[eidx[E + e]], 1);
}

__global__ __launch_bounds__(1024) void k_scan(
    const int* __restrict__ counts, int* __restrict__ offsets,
    int* __restrict__ cursor)
{
    __shared__ int part[1024];
    const int tid = threadIdx.x;
    const int CH = 20;
    const int base = tid * CH;
    int s = 0;
    for (int i = 0; i < CH; ++i) {
        int idx = base + i;
        if (idx < N) s += counts[idx];
    }
    part[tid] = s;
    __syncthreads();
    for (int off = 1; off < 1024; off <<= 1) {
        int v = (tid >= off) ? part[tid - off] : 0;
        __syncthreads();
        part[tid] += v;
        __syncthreads();
    }
    int run = (tid > 0) ? part[tid - 1] : 0;
    for (int i = 0; i < CH; ++i) {
        int idx = base + i;
        if (idx < N) {
            int c = counts[idx];
            offsets[idx] = run;
            cursor[idx] = run;
            run += c;
        }
    }
    if (tid == 0) offsets[N] = part[1023];
}

__global__ __launch_bounds__(256) void k_scatter(
    const int* __restrict__ eidx, int* __restrict__ cursor,
    int* __restrict__ perm)
{
    int e = blockIdx.x * 256 + threadIdx.x;
    if (e < E) {
        int pos = atomicAdd(&cursor[eidx[E + e]], 1);
        perm[pos] = e;
    }
}

// ---------------------------------------------------------------------------
// Weight conversion for the post-GEMMs
// ---------------------------------------------------------------------------
__global__ __launch_bounds__(256) void k_wconv(
    const float* __restrict__ W20, const float* __restrict__ Wsc0,
    const float* __restrict__ W21, const float* __restrict__ Wsc1,
    u16* __restrict__ Bt1, u16* __restrict__ Bt2)
{
    int i = blockIdx.x * 256 + threadIdx.x;
    if (i < 128 * 384) {
        int w = i / 384, k = i % 384;
        float v = (k < 128) ? W20[k * 128 + w] : Wsc0[(k - 128) * 128 + w];
        Bt1[i] = f2bf(v);
    } else {
        int j = i - 128 * 384;
        if (j < 64 * 384) {
            int w = j / 384, k = j % 384;
            float v = (k < 128) ? W21[k * 64 + w] : Wsc1[(k - 128) * 64 + w];
            Bt2[j] = f2bf(v);
        }
    }
}

// ---------------------------------------------------------------------------
// Fill xz columns (128..383) of A1 / A2
// ---------------------------------------------------------------------------
__global__ __launch_bounds__(256) void k_prep_xz(
    const float* __restrict__ x, const float* __restrict__ attrs,
    u16* __restrict__ A1, u16* __restrict__ A2)
{
    const int n = blockIdx.x;
    const int tid = threadIdx.x;
    __shared__ float xr[256];
    xr[tid] = x[(size_t)n * 256 + tid];
    __syncthreads();
    const float at = attrs[(size_t)n * 4 + (tid & 3)] * INV_SC;
    const int u = tid >> 2;
    A1[(size_t)n * 384 + 128 + tid] = f2bf(xr[u] * at);
    #pragma unroll
    for (int d = 0; d < 3; ++d)
        A2[((size_t)n * 3 + d) * 384 + 128 + tid] = f2bf(xr[64 + u * 3 + d] * at);
}

// ---------------------------------------------------------------------------
// Gather (factorized): accumulate T tensors over edges, apply Wm2 per node.
//   T1_k[c] = sum_e hid_k * a0 * g0[c]
//   T4_k[c] = sum_e hid_k * dot[c]           (dot[c] = sum_d g1_d[c] a_d)
//   T2_{d,k}[c] = sum_e hid_k * g0[c] * a_d
//   T3_{d,k}[c] = sum_e hid_k * a0 * g1_d[c]
// Finalize: s0a[c] = inv_e * sum_k Wm2[k][c]     * T1_k[c]
//           s0b[c] = inv_e * sum_k Wm2[k][192+c] * T4_k[c] * INV_SQRT3
//           s1a_d[c]= inv_e * sum_k Wm2[k][64+c] * T2_{d,k}[c]
//           s1b_d[c]= inv_e * sum_k Wm2[k][128+c]* T3_{d,k}[c]
// ---------------------------------------------------------------------------
__global__ __launch_bounds__(256) void k_gather(
    const int* __restrict__ perm, const int* __restrict__ offsets,
    const int* __restrict__ eidx,
    const float* __restrict__ eattr, const float* __restrict__ hid,
    const float* __restrict__ hc, const float* __restrict__ Wm2,
    u16* __restrict__ A1, u16* __restrict__ A2)
{
    const int lane = threadIdx.x & 63;
    const int n = blockIdx.x * 4 + (threadIdx.x >> 6);
    const int beg = offsets[n];
    const int end = offsets[n + 1];

    float T1[8] = {}, T4[8] = {};
    float T2[3][8] = {}, T3[3][8] = {};

    for (int base = beg; base < end; base += 64) {
        const int cnt = min(64, end - base);
        int e_l = 0, src_l = 0;
        float4 ea_l = make_float4(0.f, 0.f, 0.f, 0.f);
        if (lane < cnt) {
            e_l = perm[base + lane];
            src_l = eidx[e_l];
            ea_l = ((const float4*)eattr)[e_l];
        }
        for (int i = 0; i < cnt; ++i) {
            const int e   = __shfl(e_l, i, 64);
            const int src = __shfl(src_l, i, 64);
            const float a0 = __shfl(ea_l.x, i, 64);
            const float ax = __shfl(ea_l.y, i, 64);
            const float ay = __shfl(ea_l.z, i, 64);
            const float az = __shfl(ea_l.w, i, 64);

            const float4 h = ((const float4*)hc)[(size_t)src * 64 + lane];
            const float hv = hid[(size_t)e * 8 + (lane & 7)];

            const float g0 = h.x, g1x = h.y, g1y = h.z, g1z = h.w;
            const float ga   = g0 * a0;
            const float dotc = g1x * ax + g1y * ay + g1z * az;
            const float gax = g0 * ax, gay = g0 * ay, gaz = g0 * az;
            const float b1x = a0 * g1x, b1y = a0 * g1y, b1z = a0 * g1z;

            #pragma unroll
            for (int k = 0; k < 8; ++k) {
                const float hk = __shfl(hv, k, 64);
                T1[k]    += hk * ga;
                T4[k]    += hk * dotc;
                T2[0][k] += hk * gax;
                T2[1][k] += hk * gay;
                T2[2][k] += hk * gaz;
                T3[0][k] += hk * b1x;
                T3[1][k] += hk * b1y;
                T3[2][k] += hk * b1z;
            }
        }
    }

    // finalize: apply Wm2 once per node
    float s0a = 0.f, s0b = 0.f;
    float s1a[3] = {0.f, 0.f, 0.f}, s1b[3] = {0.f, 0.f, 0.f};
    #pragma unroll
    for (int k = 0; k < 8; ++k) {
        const float wA = Wm2[k * 256 + lane];
        const float wB = Wm2[k * 256 + 64 + lane];
        const float wC = Wm2[k * 256 + 128 + lane];
        const float wD = Wm2[k * 256 + 192 + lane];
        s0a += wA * T1[k];
        s0b += wD * T4[k];
        #pragma unroll
        for (int d = 0; d < 3; ++d) {
            s1a[d] += wB * T2[d][k];
            s1b[d] += wC * T3[d][k];
        }
    }

    const float f = INV_E * INV_N * INV2;   // edge-MLP scale + seg-mean + lin2 scale
    u16* a1p = &A1[(size_t)n * 384];
    a1p[lane]      = f2bf(s0a * f);
    a1p[64 + lane] = f2bf(s0b * f * INV_SQRT3);
    #pragma unroll
    for (int d = 0; d < 3; ++d) {
        u16* a2p = &A2[((size_t)n * 3 + d) * 384];
        a2p[lane]      = f2bf(s1a[d] * f);
        a2p[64 + lane] = f2bf(s1b[d] * f);
    }
}

// ---------------------------------------------------------------------------
// bf16 MFMA GEMM: C(M x NCOLS) = A(M x 384) @ Bt^T, Bt is [NCOLS][384].
// ---------------------------------------------------------------------------
template<int NCOLS>
__global__ __launch_bounds__(256) void k_gemm(
    const u16* __restrict__ A, const u16* __restrict__ Bt,
    float* __restrict__ C, int M)
{
    constexpr int NT = NCOLS / 16;
    const int lane = threadIdx.x & 63;
    const int wave = threadIdx.x >> 6;
    const int quad = lane >> 4;
    const int l16 = lane & 15;
    const int row0 = blockIdx.x * 64 + wave * 16 + l16;

    f32x4 acc[NT] = {};
    #pragma unroll
    for (int k0 = 0; k0 < 384; k0 += 32) {
        bf16x8 a;
        if (row0 < M)
            a = *(const bf16x8*)(A + (size_t)row0 * 384 + k0 + quad * 8);
        else
            a = (bf16x8){0, 0, 0, 0, 0, 0, 0, 0};
        #pragma unroll
        for (int t = 0; t < NT; ++t) {
            bf16x8 b = *(const bf16x8*)(Bt + (size_t)(t * 16 + l16) * 384 + k0 + quad * 8);
            acc[t] = __builtin_amdgcn_mfma_f32_16x16x32_bf16(a, b, acc[t], 0, 0, 0);
        }
    }
    const int rowg = blockIdx.x * 64 + wave * 16 + quad * 4;
    #pragma unroll
    for (int t = 0; t < NT; ++t) {
        #pragma unroll
        for (int r = 0; r < 4; ++r) {
            int rr = rowg + r;
            if (rr < M) C[(size_t)rr * NCOLS + t * 16 + l16] = acc[t][r];
        }
    }
}

// ---------------------------------------------------------------------------
// Epilogue
// ---------------------------------------------------------------------------
__global__ __launch_bounds__(256) void k_epilogue(
    const float* __restrict__ x,
    const float* __restrict__ t0, const float* __restrict__ t1,
    float* __restrict__ out)
{
    const int n = blockIdx.x;
    const int c = threadIdx.x;
    const float xv = x[(size_t)n * 256 + c];
    float o;
    if (c < 64) {
        o = xv + silu(t0[(size_t)n * 128 + c]);
    } else {
        int r = c - 64;
        int w = r / 3;
        int d = r - w * 3;
        o = xv + silu(t0[(size_t)n * 128 + 64 + w]) * t1[((size_t)n * 3 + d) * 64 + w];
    }
    out[(size_t)n * 256 + c] = o;
}

extern "C" void kernel_launch(void* const* d_in, const int* in_sizes, int n_in,
                              void* d_out, int out_size, void* d_ws, size_t ws_size,
                              hipStream_t stream) {
    const float* node_feats = (const float*)d_in[0];
    const float* node_attrs = (const float*)d_in[1];
    const float* edge_attrs = (const float*)d_in[2];
    const float* edge_emb   = (const float*)d_in[3];
    const float* W_lin1_0   = (const float*)d_in[4];
    const float* W_lin1_1   = (const float*)d_in[5];
    const float* W_mlp1     = (const float*)d_in[6];
    const float* W_mlp2     = (const float*)d_in[7];
    const float* W_lin2_0   = (const float*)d_in[8];
    const float* W_lin2_1   = (const float*)d_in[9];
    const float* W_sc0      = (const float*)d_in[10];
    const float* W_sc1      = (const float*)d_in[11];
    const int*   edge_index = (const int*)d_in[12];
    float* out = (float*)d_out;

    // Workspace layout. R = N*320 floats:
    //   pre-gather:  hc = R[0 : N*256]   (AoS h),  hid = R[N*256 : N*256+E*8]
    //                (E*8 == N*64 exactly, so hid fits the tail of R)
    //   post-gather: t0 = R[0 : N*128], t1 = R[N*128 : N*320] (hc/hid dead)
    float* R   = (float*)d_ws;
    float* hc  = R;
    float* hid = R + (size_t)N * 256;
    float* t0  = R;
    float* t1  = R + (size_t)N * 128;
    u16* A1  = (u16*)(R + (size_t)N * 320);      // N*384 bf16
    u16* A2  = A1 + (size_t)N * 384;             // 3N*384 bf16
    u16* Bt1 = A2 + (size_t)N * 1152;            // 128*384
    u16* Bt2 = Bt1 + 128 * 384;                  // 64*384
    int* counts  = (int*)(Bt2 + 64 * 384);       // N (reused as cursor)
    int* offsets = counts + N;                   // N+1
    int* perm    = offsets + (N + 1);            // E

    hipMemsetAsync(counts, 0, N * sizeof(int), stream);

    k_node_pre<<<N / 4, 256, 0, stream>>>(node_feats, W_lin1_0, W_lin1_1, hc);
    k_hid<<<(E * 8 + 255) / 256, 256, 0, stream>>>(edge_emb, W_mlp1, hid);
    k_hist<<<(E + 255) / 256, 256, 0, stream>>>(edge_index, counts);
    k_scan<<<1, 1024, 0, stream>>>(counts, offsets, counts);
    k_scatter<<<(E + 255) / 256, 256, 0, stream>>>(edge_index, counts, perm);
    k_wconv<<<(128 * 384 + 64 * 384 + 255) / 256, 256, 0, stream>>>(
        W_lin2_0, W_sc0, W_lin2_1, W_sc1, Bt1, Bt2);
    k_prep_xz<<<N, 256, 0, stream>>>(node_feats, node_attrs, A1, A2);
    k_gather<<<N / 4, 256, 0, stream>>>(perm, offsets, edge_index,
                                        edge_attrs, hid, hc, W_mlp2, A1, A2);
    k_gemm<128><<<(N + 63) / 64, 256, 0, stream>>>(A1, Bt1, t0, N);
    k_gemm<64><<<(3 * N + 63) / 64, 256, 0, stream>>>(A2, Bt2, t1, 3 * N);
    k_epilogue<<<N, 256, 0, stream>>>(node_feats, t0, t1, out);
}

// Round 5
// 296.510 us; speedup vs baseline: 1.8449x; 1.0480x over previous
//
#include <hip/hip_runtime.h>
#include <hip/hip_bf16.h>
#include <math.h>

#define N 20000
#define E 160000
#define MUL 64
#define EDIM 8
#define NZ 4

#define INV_SQRT_MUL 0.125f          // 1/sqrt(64)
#define INV_E 0.35355339059327373f   // 1/sqrt(8)
#define INV_N 0.35355339059327373f   // 1/sqrt(8)
#define INV2 0.08838834764831845f    // 1/sqrt(128)
#define INV_SC 0.0625f               // 1/sqrt(256)
#define INV_SQRT3 0.5773502691896258f

typedef unsigned short u16;
typedef unsigned int u32;
typedef short bf16x8 __attribute__((ext_vector_type(8)));
typedef float f32x4 __attribute__((ext_vector_type(4)));

__device__ __forceinline__ float silu(float v) {
    return v / (1.0f + __expf(-v));
}

__device__ __forceinline__ u16 f2bf(float f) {
    union { float f; unsigned int u; } v; v.f = f;
    unsigned int r = (v.u + 0x7FFFu + ((v.u >> 16) & 1u)) >> 16;
    return (u16)r;
}
__device__ __forceinline__ float bflo(u32 p) {   // low u16 -> float
    union { unsigned int u; float f; } v; v.u = p << 16; return v.f;
}
__device__ __forceinline__ float bfhi(u32 p) {   // high u16 -> float
    union { unsigned int u; float f; } v; v.u = p & 0xFFFF0000u; return v.f;
}

// ---------------------------------------------------------------------------
// Prep: per node — bf16-pack x into GEMM layouts + fill xz cols of A1/A2.
//   x0p[n][u] = bf16(x[n][u]); x1p[(n*3+d)][u] = bf16(x[n][64+3u+d])
//   A1[n][128+u*4+z] = bf16(x0[u]*attr[z]*INV_SC)
//   A2[(n*3+d)][128+u*4+z] = bf16(x1[u][d]*attr[z]*INV_SC)
// ---------------------------------------------------------------------------
__global__ __launch_bounds__(256) void k_prep(
    const float* __restrict__ x, const float* __restrict__ attrs,
    u16* __restrict__ A1, u16* __restrict__ A2,
    u16* __restrict__ x0p, u16* __restrict__ x1p)
{
    const int n = blockIdx.x;
    const int tid = threadIdx.x;
    __shared__ float xr[256];
    xr[tid] = x[(size_t)n * 256 + tid];
    __syncthreads();
    const float at = attrs[(size_t)n * 4 + (tid & 3)] * INV_SC;
    const int u = tid >> 2;
    A1[(size_t)n * 384 + 128 + tid] = f2bf(xr[u] * at);
    #pragma unroll
    for (int d = 0; d < 3; ++d)
        A2[((size_t)n * 3 + d) * 384 + 128 + tid] = f2bf(xr[64 + u * 3 + d] * at);
    if (tid < 64) {
        x0p[(size_t)n * 64 + tid] = f2bf(xr[tid]);
    } else {
        int q = tid - 64;        // 0..191
        int d = q >> 6, uu = q & 63;
        x1p[((size_t)n * 3 + d) * 64 + uu] = f2bf(xr[64 + uu * 3 + d]);
    }
}

// ---------------------------------------------------------------------------
// Weight conversion: Bt1[128][384], Bt2[64][384] for the fused post-GEMM,
// W0b[v][u] = W0[u][v]*INV_SQRT_MUL, W1b[v][u] = W1[u][v]*INV_SQRT_MUL.
// ---------------------------------------------------------------------------
__global__ __launch_bounds__(256) void k_wconv(
    const float* __restrict__ W20, const float* __restrict__ Wsc0,
    const float* __restrict__ W21, const float* __restrict__ Wsc1,
    const float* __restrict__ W0, const float* __restrict__ W1,
    u16* __restrict__ Bt1, u16* __restrict__ Bt2,
    u16* __restrict__ W0b, u16* __restrict__ W1b)
{
    int i = blockIdx.x * 256 + threadIdx.x;
    if (i < 128 * 384) {
        int w = i / 384, k = i % 384;
        float v = (k < 128) ? W20[k * 128 + w] : Wsc0[(k - 128) * 128 + w];
        Bt1[i] = f2bf(v);
    } else if (i < 128 * 384 + 64 * 384) {
        int j = i - 128 * 384;
        int w = j / 384, k = j % 384;
        float v = (k < 128) ? W21[k * 64 + w] : Wsc1[(k - 128) * 64 + w];
        Bt2[j] = f2bf(v);
    } else if (i < 128 * 384 + 64 * 384 + 4096) {
        int j = i - (128 * 384 + 64 * 384);
        int v = j >> 6, u = j & 63;
        W0b[j] = f2bf(W0[u * 64 + v] * INV_SQRT_MUL);
    } else if (i < 128 * 384 + 64 * 384 + 8192) {
        int j = i - (128 * 384 + 64 * 384 + 4096);
        int v = j >> 6, u = j & 63;
        W1b[j] = f2bf(W1[u * 64 + v] * INV_SQRT_MUL);
    }
}

// ---------------------------------------------------------------------------
// h-GEMM (MFMA): C0 (20000x64) = x0p@W0b^T, C1 (60000x64) = x1p@W1b^T.
// Output hc as bf16 AoS: hc[n][v][4] = (g0, g1x, g1y, g1z).
// 16-row wave tiles: g < 1250 -> C0, else C1. Grid 1250 blocks x 4 waves.
// ---------------------------------------------------------------------------
__global__ __launch_bounds__(256) void k_hgemm(
    const u16* __restrict__ x0p, const u16* __restrict__ x1p,
    const u16* __restrict__ W0b, const u16* __restrict__ W1b,
    u16* __restrict__ hc)
{
    const int lane = threadIdx.x & 63;
    const int g = blockIdx.x * 4 + (threadIdx.x >> 6);
    const int quad = lane >> 4, l16 = lane & 15;
    const bool isC1 = (g >= 1250);
    const int row0 = isC1 ? (g - 1250) * 16 : g * 16;
    const u16* Ap = isC1 ? (x1p + (size_t)(row0 + l16) * 64)
                         : (x0p + (size_t)(row0 + l16) * 64);
    const u16* Bp = isC1 ? W1b : W0b;

    f32x4 acc[4] = {};
    #pragma unroll
    for (int k0 = 0; k0 < 64; k0 += 32) {
        bf16x8 a = *(const bf16x8*)(Ap + k0 + quad * 8);
        #pragma unroll
        for (int ct = 0; ct < 4; ++ct) {
            bf16x8 b = *(const bf16x8*)(Bp + (size_t)(ct * 16 + l16) * 64 + k0 + quad * 8);
            acc[ct] = __builtin_amdgcn_mfma_f32_16x16x32_bf16(a, b, acc[ct], 0, 0, 0);
        }
    }
    #pragma unroll
    for (int ct = 0; ct < 4; ++ct) {
        #pragma unroll
        for (int r = 0; r < 4; ++r) {
            int row = row0 + quad * 4 + r;
            int v = ct * 16 + l16;
            if (!isC1) {
                hc[(size_t)row * 256 + v * 4] = f2bf(acc[ct][r]);
            } else {
                int n = row / 3, d = row - 3 * (row / 3);
                hc[(size_t)n * 256 + v * 4 + 1 + d] = f2bf(acc[ct][r]);
            }
        }
    }
}

// ---------------------------------------------------------------------------
// Dense edge-MLP hidden layer: hid[e][k] = silu(inv_e * (emb[e] @ Wm1)[k])
// ---------------------------------------------------------------------------
__global__ __launch_bounds__(256) void k_hid(
    const float* __restrict__ eemb, const float* __restrict__ Wm1,
    float* __restrict__ hid)
{
    int i = blockIdx.x * 256 + threadIdx.x;
    if (i < E * 8) {
        int e = i >> 3, k = i & 7;
        float s = 0.f;
        #pragma unroll
        for (int j = 0; j < 8; ++j)
            s += eemb[(size_t)e * 8 + j] * Wm1[j * 8 + k];
        hid[i] = silu(s * INV_E);
    }
}

// ---------------------------------------------------------------------------
// CSR build: histogram -> scan -> scatter permutation
// ---------------------------------------------------------------------------
__global__ __launch_bounds__(256) void k_hist(
    const int* __restrict__ eidx, int* __restrict__ counts)
{
    int e = blockIdx.x * 256 + threadIdx.x;
    if (e < E) atomicAdd(&counts[eidx[E + e]], 1);
}

__global__ __launch_bounds__(1024) void k_scan(
    const int* __restrict__ counts, int* __restrict__ offsets,
    int* __restrict__ cursor)
{
    __shared__ int part[1024];
    const int tid = threadIdx.x;
    const int CH = 20;
    const int base = tid * CH;
    int s = 0;
    for (int i = 0; i < CH; ++i) {
        int idx = base + i;
        if (idx < N) s += counts[idx];
    }
    part[tid] = s;
    __syncthreads();
    for (int off = 1; off < 1024; off <<= 1) {
        int v = (tid >= off) ? part[tid - off] : 0;
        __syncthreads();
        part[tid] += v;
        __syncthreads();
    }
    int run = (tid > 0) ? part[tid - 1] : 0;
    for (int i = 0; i < CH; ++i) {
        int idx = base + i;
        if (idx < N) {
            int c = counts[idx];
            offsets[idx] = run;
            cursor[idx] = run;
            run += c;
        }
    }
    if (tid == 0) offsets[N] = part[1023];
}

__global__ __launch_bounds__(256) void k_scatter(
    const int* __restrict__ eidx, int* __restrict__ cursor,
    int* __restrict__ perm)
{
    int e = blockIdx.x * 256 + threadIdx.x;
    if (e < E) {
        int pos = atomicAdd(&cursor[eidx[E + e]], 1);
        perm[pos] = e;
    }
}

// ---------------------------------------------------------------------------
// Gather v3: one wave per dst node. Wm2 in registers (32/lane); per edge:
// broadcast loads of hid/eattr, bf16 hc row gather (8 B/lane), direct w1..w4.
// Writes bf16 A1 cols 0..127 and A2 cols 0..127 (scales folded).
// ---------------------------------------------------------------------------
__global__ __launch_bounds__(256) void k_gather(
    const int* __restrict__ perm, const int* __restrict__ offsets,
    const int* __restrict__ eidx,
    const float* __restrict__ eattr, const float* __restrict__ hid,
    const u32* __restrict__ hc2, const float* __restrict__ Wm2,
    u16* __restrict__ A1, u16* __restrict__ A2)
{
    const int lane = threadIdx.x & 63;
    const int n = blockIdx.x * 4 + (threadIdx.x >> 6);
    const int beg = offsets[n];
    const int end = offsets[n + 1];

    float wm0[8], wm1[8], wm2r[8], wm3[8];
    #pragma unroll
    for (int k = 0; k < 8; ++k) {
        wm0[k]  = Wm2[k * 256 + lane];
        wm1[k]  = Wm2[k * 256 + 64 + lane];
        wm2r[k] = Wm2[k * 256 + 128 + lane];
        wm3[k]  = Wm2[k * 256 + 192 + lane];
    }

    float acc0a = 0.f, acc0b = 0.f;
    float s1a[3] = {0.f, 0.f, 0.f}, s1b[3] = {0.f, 0.f, 0.f};

    for (int base = beg; base < end; base += 64) {
        const int cnt = min(64, end - base);
        int e_l = 0, src_l = 0;
        if (lane < cnt) {
            e_l = perm[base + lane];
            src_l = eidx[e_l];
        }
        for (int i = 0; i < cnt; ++i) {
            const int e   = __shfl(e_l, i, 64);
            const int src = __shfl(src_l, i, 64);

            const float4 ea = ((const float4*)eattr)[e];
            const float4 hA = ((const float4*)hid)[(size_t)e * 2];
            const float4 hB = ((const float4*)hid)[(size_t)e * 2 + 1];

            float w1 = hA.x * wm0[0] + hA.y * wm0[1] + hA.z * wm0[2] + hA.w * wm0[3]
                     + hB.x * wm0[4] + hB.y * wm0[5] + hB.z * wm0[6] + hB.w * wm0[7];
            float w2 = hA.x * wm1[0] + hA.y * wm1[1] + hA.z * wm1[2] + hA.w * wm1[3]
                     + hB.x * wm1[4] + hB.y * wm1[5] + hB.z * wm1[6] + hB.w * wm1[7];
            float w3 = hA.x * wm2r[0] + hA.y * wm2r[1] + hA.z * wm2r[2] + hA.w * wm2r[3]
                     + hB.x * wm2r[4] + hB.y * wm2r[5] + hB.z * wm2r[6] + hB.w * wm2r[7];
            float w4 = hA.x * wm3[0] + hA.y * wm3[1] + hA.z * wm3[2] + hA.w * wm3[3]
                     + hB.x * wm3[4] + hB.y * wm3[5] + hB.z * wm3[6] + hB.w * wm3[7];

            const uint2 hp = ((const uint2*)hc2)[(size_t)src * 64 + lane];
            const float g0  = bflo(hp.x), g1x = bfhi(hp.x);
            const float g1y = bflo(hp.y), g1z = bfhi(hp.y);

            acc0a += w1 * g0 * ea.x;
            const float dotc = g1x * ea.y + g1y * ea.z + g1z * ea.w;
            acc0b += w4 * dotc;
            const float wg  = w2 * g0;
            const float w3a = w3 * ea.x;
            s1a[0] += wg * ea.y;  s1a[1] += wg * ea.z;  s1a[2] += wg * ea.w;
            s1b[0] += w3a * g1x;  s1b[1] += w3a * g1y;  s1b[2] += w3a * g1z;
        }
    }

    const float f = INV_E * INV_N * INV2;
    u16* a1p = &A1[(size_t)n * 384];
    a1p[lane]      = f2bf(acc0a * f);
    a1p[64 + lane] = f2bf(acc0b * f * INV_SQRT3);
    #pragma unroll
    for (int d = 0; d < 3; ++d) {
        u16* a2p = &A2[((size_t)n * 3 + d) * 384];
        a2p[lane]      = f2bf(s1a[d] * f);
        a2p[64 + lane] = f2bf(s1b[d] * f);
    }
}

// ---------------------------------------------------------------------------
// Fused post-GEMM + epilogue. 32 nodes per block (grid 625), 4 waves.
// t0 (32x128) and t1 (96x64) computed via MFMA into LDS, then gated output.
// ---------------------------------------------------------------------------
__global__ __launch_bounds__(256) void k_gemm_fused(
    const u16* __restrict__ A1, const u16* __restrict__ A2,
    const u16* __restrict__ Bt1, const u16* __restrict__ Bt2,
    const float* __restrict__ x, float* __restrict__ out)
{
    const int lane = threadIdx.x & 63;
    const int wave = threadIdx.x >> 6;
    const int quad = lane >> 4, l16 = lane & 15;
    const int n0 = blockIdx.x * 32;

    __shared__ float st0[32][130];
    __shared__ float st1[96][66];

    f32x4 acc[10] = {};
    #pragma unroll
    for (int j = 0; j < 10; ++j) {
        const u16 *Ap, *Bp;
        if (j < 4) {                       // t0 unit: u = wave + 4j in 0..15
            int u = wave + 4 * j;
            int rt = u >> 3, ct = u & 7;
            Ap = A1 + (size_t)(n0 + rt * 16 + l16) * 384;
            Bp = Bt1 + (size_t)(ct * 16 + l16) * 384;
        } else {                           // t1 unit: v = wave + 4(j-4) in 0..23
            int v = wave + 4 * (j - 4);
            int rt = v >> 2, ct = v & 3;
            Ap = A2 + (size_t)(3 * n0 + rt * 16 + l16) * 384;
            Bp = Bt2 + (size_t)(ct * 16 + l16) * 384;
        }
        #pragma unroll
        for (int k0 = 0; k0 < 384; k0 += 32) {
            bf16x8 a = *(const bf16x8*)(Ap + k0 + quad * 8);
            bf16x8 b = *(const bf16x8*)(Bp + k0 + quad * 8);
            acc[j] = __builtin_amdgcn_mfma_f32_16x16x32_bf16(a, b, acc[j], 0, 0, 0);
        }
    }
    #pragma unroll
    for (int j = 0; j < 10; ++j) {
        if (j < 4) {
            int u = wave + 4 * j;
            int rt = u >> 3, ct = u & 7;
            #pragma unroll
            for (int r = 0; r < 4; ++r)
                st0[rt * 16 + quad * 4 + r][ct * 16 + l16] = acc[j][r];
        } else {
            int v = wave + 4 * (j - 4);
            int rt = v >> 2, ct = v & 3;
            #pragma unroll
            for (int r = 0; r < 4; ++r)
                st1[rt * 16 + quad * 4 + r][ct * 16 + l16] = acc[j][r];
        }
    }
    __syncthreads();

    for (int idx = threadIdx.x; idx < 32 * 256; idx += 256) {
        int t = idx >> 8, c = idx & 255;
        float xv = x[(size_t)(n0 + t) * 256 + c];
        float o;
        if (c < 64) {
            o = xv + silu(st0[t][c]);
        } else {
            int r = c - 64;                 // 0..191
            int w = (r * 21846) >> 16;      // r/3
            int d = r - w * 3;
            o = xv + silu(st0[t][64 + w]) * st1[t * 3 + d][w];
        }
        out[(size_t)(n0 + t) * 256 + c] = o;
    }
}

extern "C" void kernel_launch(void* const* d_in, const int* in_sizes, int n_in,
                              void* d_out, int out_size, void* d_ws, size_t ws_size,
                              hipStream_t stream) {
    const float* node_feats = (const float*)d_in[0];
    const float* node_attrs = (const float*)d_in[1];
    const float* edge_attrs = (const float*)d_in[2];
    const float* edge_emb   = (const float*)d_in[3];
    const float* W_lin1_0   = (const float*)d_in[4];
    const float* W_lin1_1   = (const float*)d_in[5];
    const float* W_mlp1     = (const float*)d_in[6];
    const float* W_mlp2     = (const float*)d_in[7];
    const float* W_lin2_0   = (const float*)d_in[8];
    const float* W_lin2_1   = (const float*)d_in[9];
    const float* W_sc0      = (const float*)d_in[10];
    const float* W_sc1      = (const float*)d_in[11];
    const int*   edge_index = (const int*)d_in[12];
    float* out = (float*)d_out;

    char* p = (char*)d_ws;
    float* hid = (float*)p;                 p += (size_t)E * 8 * 4;        // 5.12 MB
    u16* hc    = (u16*)p;                   p += (size_t)N * 256 * 2;      // 10.24 MB
    u16* A1    = (u16*)p;                   p += (size_t)N * 384 * 2;      // 15.36 MB
    u16* A2    = (u16*)p;                   p += (size_t)N * 3 * 384 * 2;  // 46.08 MB
    u16* x0p   = (u16*)p;                   p += (size_t)N * 64 * 2;
    u16* x1p   = (u16*)p;                   p += (size_t)N * 3 * 64 * 2;
    u16* Bt1   = (u16*)p;                   p += 128 * 384 * 2;
    u16* Bt2   = (u16*)p;                   p += 64 * 384 * 2;
    u16* W0b   = (u16*)p;                   p += 4096 * 2;
    u16* W1b   = (u16*)p;                   p += 4096 * 2;
    int* counts  = (int*)p;                 p += N * 4;
    int* offsets = (int*)p;                 p += (N + 1) * 4;
    int* perm    = (int*)p;                 p += E * 4;

    hipMemsetAsync(counts, 0, N * sizeof(int), stream);

    k_prep<<<N, 256, 0, stream>>>(node_feats, node_attrs, A1, A2, x0p, x1p);
    k_wconv<<<(128 * 384 + 64 * 384 + 8192 + 255) / 256, 256, 0, stream>>>(
        W_lin2_0, W_sc0, W_lin2_1, W_sc1, W_lin1_0, W_lin1_1, Bt1, Bt2, W0b, W1b);
    k_hid<<<(E * 8 + 255) / 256, 256, 0, stream>>>(edge_emb, W_mlp1, hid);
    k_hist<<<(E + 255) / 256, 256, 0, stream>>>(edge_index, counts);
    k_scan<<<1, 1024, 0, stream>>>(counts, offsets, counts);
    k_scatter<<<(E + 255) / 256, 256, 0, stream>>>(edge_index, counts, perm);
    k_hgemm<<<1250, 256, 0, stream>>>(x0p, x1p, W0b, W1b, hc);
    k_gather<<<N / 4, 256, 0, stream>>>(perm, offsets, edge_index,
                                        edge_attrs, hid, (const u32*)hc, W_mlp2, A1, A2);
    k_gemm_fused<<<625, 256, 0, stream>>>(A1, A2, Bt1, Bt2, node_feats, out);
}

// Round 6
// 289.989 us; speedup vs baseline: 1.8864x; 1.0225x over previous
//
#include <hip/hip_runtime.h>
#include <hip/hip_bf16.h>
#include <math.h>

#define N 20000
#define E 160000
#define MUL 64
#define EDIM 8
#define NZ 4

#define INV_SQRT_MUL 0.125f          // 1/sqrt(64)
#define INV_E 0.35355339059327373f   // 1/sqrt(8)
#define INV_N 0.35355339059327373f   // 1/sqrt(8)
#define INV2 0.08838834764831845f    // 1/sqrt(128)
#define INV_SC 0.0625f               // 1/sqrt(256)
#define INV_SQRT3 0.5773502691896258f

typedef unsigned short u16;
typedef unsigned int u32;
typedef short bf16x8 __attribute__((ext_vector_type(8)));
typedef float f32x4 __attribute__((ext_vector_type(4)));

__device__ __forceinline__ float silu(float v) {
    return v / (1.0f + __expf(-v));
}

__device__ __forceinline__ u16 f2bf(float f) {
    union { float f; unsigned int u; } v; v.f = f;
    unsigned int r = (v.u + 0x7FFFu + ((v.u >> 16) & 1u)) >> 16;
    return (u16)r;
}
__device__ __forceinline__ float bflo(u32 p) {
    union { unsigned int u; float f; } v; v.u = p << 16; return v.f;
}
__device__ __forceinline__ float bfhi(u32 p) {
    union { unsigned int u; float f; } v; v.u = p & 0xFFFF0000u; return v.f;
}

// ---------------------------------------------------------------------------
// Prep: per node — bf16-pack x into GEMM layouts + fill xz cols of A1/A2.
// ---------------------------------------------------------------------------
__global__ __launch_bounds__(256) void k_prep(
    const float* __restrict__ x, const float* __restrict__ attrs,
    u16* __restrict__ A1, u16* __restrict__ A2,
    u16* __restrict__ x0p, u16* __restrict__ x1p)
{
    const int n = blockIdx.x;
    const int tid = threadIdx.x;
    __shared__ float xr[256];
    xr[tid] = x[(size_t)n * 256 + tid];
    __syncthreads();
    const float at = attrs[(size_t)n * 4 + (tid & 3)] * INV_SC;
    const int u = tid >> 2;
    A1[(size_t)n * 384 + 128 + tid] = f2bf(xr[u] * at);
    #pragma unroll
    for (int d = 0; d < 3; ++d)
        A2[((size_t)n * 3 + d) * 384 + 128 + tid] = f2bf(xr[64 + u * 3 + d] * at);
    if (tid < 64) {
        x0p[(size_t)n * 64 + tid] = f2bf(xr[tid]);
    } else {
        int q = tid - 64;
        int d = q >> 6, uu = q & 63;
        x1p[((size_t)n * 3 + d) * 64 + uu] = f2bf(xr[64 + uu * 3 + d]);
    }
}

// ---------------------------------------------------------------------------
// Weight conversion
// ---------------------------------------------------------------------------
__global__ __launch_bounds__(256) void k_wconv(
    const float* __restrict__ W20, const float* __restrict__ Wsc0,
    const float* __restrict__ W21, const float* __restrict__ Wsc1,
    const float* __restrict__ W0, const float* __restrict__ W1,
    u16* __restrict__ Bt1, u16* __restrict__ Bt2,
    u16* __restrict__ W0b, u16* __restrict__ W1b)
{
    int i = blockIdx.x * 256 + threadIdx.x;
    if (i < 128 * 384) {
        int w = i / 384, k = i % 384;
        float v = (k < 128) ? W20[k * 128 + w] : Wsc0[(k - 128) * 128 + w];
        Bt1[i] = f2bf(v);
    } else if (i < 128 * 384 + 64 * 384) {
        int j = i - 128 * 384;
        int w = j / 384, k = j % 384;
        float v = (k < 128) ? W21[k * 64 + w] : Wsc1[(k - 128) * 64 + w];
        Bt2[j] = f2bf(v);
    } else if (i < 128 * 384 + 64 * 384 + 4096) {
        int j = i - (128 * 384 + 64 * 384);
        int v = j >> 6, u = j & 63;
        W0b[j] = f2bf(W0[u * 64 + v] * INV_SQRT_MUL);
    } else if (i < 128 * 384 + 64 * 384 + 8192) {
        int j = i - (128 * 384 + 64 * 384 + 4096);
        int v = j >> 6, u = j & 63;
        W1b[j] = f2bf(W1[u * 64 + v] * INV_SQRT_MUL);
    }
}

// ---------------------------------------------------------------------------
// h-GEMM (MFMA): hc bf16 AoS hc[n][v][4] = (g0, g1x, g1y, g1z).
// ---------------------------------------------------------------------------
__global__ __launch_bounds__(256) void k_hgemm(
    const u16* __restrict__ x0p, const u16* __restrict__ x1p,
    const u16* __restrict__ W0b, const u16* __restrict__ W1b,
    u16* __restrict__ hc)
{
    const int lane = threadIdx.x & 63;
    const int g = blockIdx.x * 4 + (threadIdx.x >> 6);
    const int quad = lane >> 4, l16 = lane & 15;
    const bool isC1 = (g >= 1250);
    const int row0 = isC1 ? (g - 1250) * 16 : g * 16;
    const u16* Ap = isC1 ? (x1p + (size_t)(row0 + l16) * 64)
                         : (x0p + (size_t)(row0 + l16) * 64);
    const u16* Bp = isC1 ? W1b : W0b;

    f32x4 acc[4] = {};
    #pragma unroll
    for (int k0 = 0; k0 < 64; k0 += 32) {
        bf16x8 a = *(const bf16x8*)(Ap + k0 + quad * 8);
        #pragma unroll
        for (int ct = 0; ct < 4; ++ct) {
            bf16x8 b = *(const bf16x8*)(Bp + (size_t)(ct * 16 + l16) * 64 + k0 + quad * 8);
            acc[ct] = __builtin_amdgcn_mfma_f32_16x16x32_bf16(a, b, acc[ct], 0, 0, 0);
        }
    }
    #pragma unroll
    for (int ct = 0; ct < 4; ++ct) {
        #pragma unroll
        for (int r = 0; r < 4; ++r) {
            int row = row0 + quad * 4 + r;
            int v = ct * 16 + l16;
            if (!isC1) {
                hc[(size_t)row * 256 + v * 4] = f2bf(acc[ct][r]);
            } else {
                int n = row / 3, d = row - 3 * (row / 3);
                hc[(size_t)n * 256 + v * 4 + 1 + d] = f2bf(acc[ct][r]);
            }
        }
    }
}

// ---------------------------------------------------------------------------
// Dense edge-MLP hidden layer
// ---------------------------------------------------------------------------
__global__ __launch_bounds__(256) void k_hid(
    const float* __restrict__ eemb, const float* __restrict__ Wm1,
    float* __restrict__ hid)
{
    int i = blockIdx.x * 256 + threadIdx.x;
    if (i < E * 8) {
        int e = i >> 3, k = i & 7;
        float s = 0.f;
        #pragma unroll
        for (int j = 0; j < 8; ++j)
            s += eemb[(size_t)e * 8 + j] * Wm1[j * 8 + k];
        hid[i] = silu(s * INV_E);
    }
}

// ---------------------------------------------------------------------------
// CSR build: histogram -> scan -> scatter permutation
// ---------------------------------------------------------------------------
__global__ __launch_bounds__(256) void k_hist(
    const int* __restrict__ eidx, int* __restrict__ counts)
{
    int e = blockIdx.x * 256 + threadIdx.x;
    if (e < E) atomicAdd(&counts[eidx[E + e]], 1);
}

__global__ __launch_bounds__(1024) void k_scan(
    const int* __restrict__ counts, int* __restrict__ offsets,
    int* __restrict__ cursor)
{
    __shared__ int part[1024];
    const int tid = threadIdx.x;
    const int CH = 20;
    const int base = tid * CH;
    int s = 0;
    for (int i = 0; i < CH; ++i) {
        int idx = base + i;
        if (idx < N) s += counts[idx];
    }
    part[tid] = s;
    __syncthreads();
    for (int off = 1; off < 1024; off <<= 1) {
        int v = (tid >= off) ? part[tid - off] : 0;
        __syncthreads();
        part[tid] += v;
        __syncthreads();
    }
    int run = (tid > 0) ? part[tid - 1] : 0;
    for (int i = 0; i < CH; ++i) {
        int idx = base + i;
        if (idx < N) {
            int c = counts[idx];
            offsets[idx] = run;
            cursor[idx] = run;
            run += c;
        }
    }
    if (tid == 0) offsets[N] = part[1023];
}

__global__ __launch_bounds__(256) void k_scatter(
    const int* __restrict__ eidx, int* __restrict__ cursor,
    int* __restrict__ perm)
{
    int e = blockIdx.x * 256 + threadIdx.x;
    if (e < E) {
        int pos = atomicAdd(&cursor[eidx[E + e]], 1);
        perm[pos] = e;
    }
}

// ---------------------------------------------------------------------------
// Gather v3: one wave per dst node; Wm2 in registers; bf16 hc row gather.
// ---------------------------------------------------------------------------
__global__ __launch_bounds__(256) void k_gather(
    const int* __restrict__ perm, const int* __restrict__ offsets,
    const int* __restrict__ eidx,
    const float* __restrict__ eattr, const float* __restrict__ hid,
    const u32* __restrict__ hc2, const float* __restrict__ Wm2,
    u16* __restrict__ A1, u16* __restrict__ A2)
{
    const int lane = threadIdx.x & 63;
    const int n = blockIdx.x * 4 + (threadIdx.x >> 6);
    const int beg = offsets[n];
    const int end = offsets[n + 1];

    float wm0[8], wm1[8], wm2r[8], wm3[8];
    #pragma unroll
    for (int k = 0; k < 8; ++k) {
        wm0[k]  = Wm2[k * 256 + lane];
        wm1[k]  = Wm2[k * 256 + 64 + lane];
        wm2r[k] = Wm2[k * 256 + 128 + lane];
        wm3[k]  = Wm2[k * 256 + 192 + lane];
    }

    float acc0a = 0.f, acc0b = 0.f;
    float s1a[3] = {0.f, 0.f, 0.f}, s1b[3] = {0.f, 0.f, 0.f};

    for (int base = beg; base < end; base += 64) {
        const int cnt = min(64, end - base);
        int e_l = 0, src_l = 0;
        if (lane < cnt) {
            e_l = perm[base + lane];
            src_l = eidx[e_l];
        }
        for (int i = 0; i < cnt; ++i) {
            const int e   = __shfl(e_l, i, 64);
            const int src = __shfl(src_l, i, 64);

            const float4 ea = ((const float4*)eattr)[e];
            const float4 hA = ((const float4*)hid)[(size_t)e * 2];
            const float4 hB = ((const float4*)hid)[(size_t)e * 2 + 1];

            float w1 = hA.x * wm0[0] + hA.y * wm0[1] + hA.z * wm0[2] + hA.w * wm0[3]
                     + hB.x * wm0[4] + hB.y * wm0[5] + hB.z * wm0[6] + hB.w * wm0[7];
            float w2 = hA.x * wm1[0] + hA.y * wm1[1] + hA.z * wm1[2] + hA.w * wm1[3]
                     + hB.x * wm1[4] + hB.y * wm1[5] + hB.z * wm1[6] + hB.w * wm1[7];
            float w3 = hA.x * wm2r[0] + hA.y * wm2r[1] + hA.z * wm2r[2] + hA.w * wm2r[3]
                     + hB.x * wm2r[4] + hB.y * wm2r[5] + hB.z * wm2r[6] + hB.w * wm2r[7];
            float w4 = hA.x * wm3[0] + hA.y * wm3[1] + hA.z * wm3[2] + hA.w * wm3[3]
                     + hB.x * wm3[4] + hB.y * wm3[5] + hB.z * wm3[6] + hB.w * wm3[7];

            const uint2 hp = ((const uint2*)hc2)[(size_t)src * 64 + lane];
            const float g0  = bflo(hp.x), g1x = bfhi(hp.x);
            const float g1y = bflo(hp.y), g1z = bfhi(hp.y);

            acc0a += w1 * g0 * ea.x;
            const float dotc = g1x * ea.y + g1y * ea.z + g1z * ea.w;
            acc0b += w4 * dotc;
            const float wg  = w2 * g0;
            const float w3a = w3 * ea.x;
            s1a[0] += wg * ea.y;  s1a[1] += wg * ea.z;  s1a[2] += wg * ea.w;
            s1b[0] += w3a * g1x;  s1b[1] += w3a * g1y;  s1b[2] += w3a * g1z;
        }
    }

    const float f = INV_E * INV_N * INV2;
    u16* a1p = &A1[(size_t)n * 384];
    a1p[lane]      = f2bf(acc0a * f);
    a1p[64 + lane] = f2bf(acc0b * f * INV_SQRT3);
    #pragma unroll
    for (int d = 0; d < 3; ++d) {
        u16* a2p = &A2[((size_t)n * 3 + d) * 384];
        a2p[lane]      = f2bf(s1a[d] * f);
        a2p[64 + lane] = f2bf(s1b[d] * f);
    }
}

// ---------------------------------------------------------------------------
// Fused post-GEMM + epilogue, v2: 16 nodes/block (grid 1250), 4 waves.
// Each wave: 5 MFMA units with operand sharing —
//   t0: ct = wave, wave+4  (shared A1 fragment, rt = 0)
//   t1: rt = 0,1,2 at ct = wave (shared Bt2 fragment)
// Single k-loop issues 7 independent loads + 5 MFMAs per k-step.
// ---------------------------------------------------------------------------
__global__ __launch_bounds__(256) void k_gemm_fused(
    const u16* __restrict__ A1, const u16* __restrict__ A2,
    const u16* __restrict__ Bt1, const u16* __restrict__ Bt2,
    const float* __restrict__ x, float* __restrict__ out)
{
    const int lane = threadIdx.x & 63;
    const int wave = threadIdx.x >> 6;
    const int quad = lane >> 4, l16 = lane & 15;
    const int n0 = blockIdx.x * 16;

    __shared__ float st0[16][130];
    __shared__ float st1[48][66];

    const u16* a0p = A1  + (size_t)(n0 + l16) * 384;
    const u16* b0p = Bt1 + (size_t)(wave * 16 + l16) * 384;
    const u16* b1p = Bt1 + (size_t)((wave + 4) * 16 + l16) * 384;
    const u16* a1p = A2  + (size_t)(3 * n0 + l16) * 384;
    const u16* a2p = A2  + (size_t)(3 * n0 + 16 + l16) * 384;
    const u16* a3p = A2  + (size_t)(3 * n0 + 32 + l16) * 384;
    const u16* b2p = Bt2 + (size_t)(wave * 16 + l16) * 384;

    f32x4 acc0 = {}, acc1 = {}, acc2 = {}, acc3 = {}, acc4 = {};
    #pragma unroll
    for (int k0 = 0; k0 < 384; k0 += 32) {
        const int off = k0 + quad * 8;
        bf16x8 a0 = *(const bf16x8*)(a0p + off);
        bf16x8 b0 = *(const bf16x8*)(b0p + off);
        bf16x8 b1 = *(const bf16x8*)(b1p + off);
        bf16x8 a1 = *(const bf16x8*)(a1p + off);
        bf16x8 a2 = *(const bf16x8*)(a2p + off);
        bf16x8 a3 = *(const bf16x8*)(a3p + off);
        bf16x8 b2 = *(const bf16x8*)(b2p + off);
        acc0 = __builtin_amdgcn_mfma_f32_16x16x32_bf16(a0, b0, acc0, 0, 0, 0);
        acc1 = __builtin_amdgcn_mfma_f32_16x16x32_bf16(a0, b1, acc1, 0, 0, 0);
        acc2 = __builtin_amdgcn_mfma_f32_16x16x32_bf16(a1, b2, acc2, 0, 0, 0);
        acc3 = __builtin_amdgcn_mfma_f32_16x16x32_bf16(a2, b2, acc3, 0, 0, 0);
        acc4 = __builtin_amdgcn_mfma_f32_16x16x32_bf16(a3, b2, acc4, 0, 0, 0);
    }
    #pragma unroll
    for (int r = 0; r < 4; ++r) {
        st0[quad * 4 + r][wave * 16 + l16]       = acc0[r];
        st0[quad * 4 + r][(wave + 4) * 16 + l16] = acc1[r];
        st1[quad * 4 + r][wave * 16 + l16]       = acc2[r];
        st1[16 + quad * 4 + r][wave * 16 + l16]  = acc3[r];
        st1[32 + quad * 4 + r][wave * 16 + l16]  = acc4[r];
    }
    __syncthreads();

    for (int idx = threadIdx.x; idx < 16 * 256; idx += 256) {
        int t = idx >> 8, c = idx & 255;
        float xv = x[(size_t)(n0 + t) * 256 + c];
        float o;
        if (c < 64) {
            o = xv + silu(st0[t][c]);
        } else {
            int r = c - 64;
            int w = (r * 21846) >> 16;      // r/3
            int d = r - w * 3;
            o = xv + silu(st0[t][64 + w]) * st1[t * 3 + d][w];
        }
        out[(size_t)(n0 + t) * 256 + c] = o;
    }
}

extern "C" void kernel_launch(void* const* d_in, const int* in_sizes, int n_in,
                              void* d_out, int out_size, void* d_ws, size_t ws_size,
                              hipStream_t stream) {
    const float* node_feats = (const float*)d_in[0];
    const float* node_attrs = (const float*)d_in[1];
    const float* edge_attrs = (const float*)d_in[2];
    const float* edge_emb   = (const float*)d_in[3];
    const float* W_lin1_0   = (const float*)d_in[4];
    const float* W_lin1_1   = (const float*)d_in[5];
    const float* W_mlp1     = (const float*)d_in[6];
    const float* W_mlp2     = (const float*)d_in[7];
    const float* W_lin2_0   = (const float*)d_in[8];
    const float* W_lin2_1   = (const float*)d_in[9];
    const float* W_sc0      = (const float*)d_in[10];
    const float* W_sc1      = (const float*)d_in[11];
    const int*   edge_index = (const int*)d_in[12];
    float* out = (float*)d_out;

    char* p = (char*)d_ws;
    float* hid = (float*)p;                 p += (size_t)E * 8 * 4;
    u16* hc    = (u16*)p;                   p += (size_t)N * 256 * 2;
    u16* A1    = (u16*)p;                   p += (size_t)N * 384 * 2;
    u16* A2    = (u16*)p;                   p += (size_t)N * 3 * 384 * 2;
    u16* x0p   = (u16*)p;                   p += (size_t)N * 64 * 2;
    u16* x1p   = (u16*)p;                   p += (size_t)N * 3 * 64 * 2;
    u16* Bt1   = (u16*)p;                   p += 128 * 384 * 2;
    u16* Bt2   = (u16*)p;                   p += 64 * 384 * 2;
    u16* W0b   = (u16*)p;                   p += 4096 * 2;
    u16* W1b   = (u16*)p;                   p += 4096 * 2;
    int* counts  = (int*)p;                 p += N * 4;
    int* offsets = (int*)p;                 p += (N + 1) * 4;
    int* perm    = (int*)p;                 p += E * 4;

    hipMemsetAsync(counts, 0, N * sizeof(int), stream);

    k_prep<<<N, 256, 0, stream>>>(node_feats, node_attrs, A1, A2, x0p, x1p);
    k_wconv<<<(128 * 384 + 64 * 384 + 8192 + 255) / 256, 256, 0, stream>>>(
        W_lin2_0, W_sc0, W_lin2_1, W_sc1, W_lin1_0, W_lin1_1, Bt1, Bt2, W0b, W1b);
    k_hid<<<(E * 8 + 255) / 256, 256, 0, stream>>>(edge_emb, W_mlp1, hid);
    k_hist<<<(E + 255) / 256, 256, 0, stream>>>(edge_index, counts);
    k_scan<<<1, 1024, 0, stream>>>(counts, offsets, counts);
    k_scatter<<<(E + 255) / 256, 256, 0, stream>>>(edge_index, counts, perm);
    k_hgemm<<<1250, 256, 0, stream>>>(x0p, x1p, W0b, W1b, hc);
    k_gather<<<N / 4, 256, 0, stream>>>(perm, offsets, edge_index,
                                        edge_attrs, hid, (const u32*)hc, W_mlp2, A1, A2);
    k_gemm_fused<<<1250, 256, 0, stream>>>(A1, A2, Bt1, Bt2, node_feats, out);
}

// Round 7
// 264.967 us; speedup vs baseline: 2.0645x; 1.0944x over previous
//
#include <hip/hip_runtime.h>
#include <hip/hip_bf16.h>
#include <math.h>

#define N 20000
#define E 160000
#define MUL 64
#define EDIM 8
#define NZ 4

#define INV_SQRT_MUL 0.125f          // 1/sqrt(64)
#define INV_E 0.35355339059327373f   // 1/sqrt(8)
#define INV_N 0.35355339059327373f   // 1/sqrt(8)
#define INV2 0.08838834764831845f    // 1/sqrt(128)
#define INV_SC 0.0625f               // 1/sqrt(256)
#define INV_SQRT3 0.5773502691896258f

typedef unsigned short u16;
typedef unsigned int u32;
typedef short bf16x8 __attribute__((ext_vector_type(8)));
typedef float f32x4 __attribute__((ext_vector_type(4)));

__device__ __forceinline__ float silu(float v) {
    return v / (1.0f + __expf(-v));
}

__device__ __forceinline__ u16 f2bf(float f) {
    union { float f; unsigned int u; } v; v.f = f;
    unsigned int r = (v.u + 0x7FFFu + ((v.u >> 16) & 1u)) >> 16;
    return (u16)r;
}
__device__ __forceinline__ float bflo(u32 p) {
    union { unsigned int u; float f; } v; v.u = p << 16; return v.f;
}
__device__ __forceinline__ float bfhi(u32 p) {
    union { unsigned int u; float f; } v; v.u = p & 0xFFFF0000u; return v.f;
}

// ---------------------------------------------------------------------------
// Front kernel: grid-partitioned [prep | wconv | hid | hist].
//   prep:  blocks [0, 5000)      — 4 nodes/block, pack x -> bf16 + xz cols
//   wconv: blocks [5000, 5320)   — weight transposes/casts
//   hid:   blocks [5320, 10320)  — edge-MLP hidden layer
//   hist:  blocks [10320, 10945) — dst-degree histogram
// ---------------------------------------------------------------------------
#define PREP_B  5000
#define WCONV_B 320
#define HID_B   5000
#define HIST_B  625

__global__ __launch_bounds__(256) void k_front(
    const float* __restrict__ x, const float* __restrict__ attrs,
    const float* __restrict__ eemb, const int* __restrict__ eidx,
    const float* __restrict__ W20, const float* __restrict__ Wsc0,
    const float* __restrict__ W21, const float* __restrict__ Wsc1,
    const float* __restrict__ W0, const float* __restrict__ W1,
    const float* __restrict__ Wm1,
    u16* __restrict__ A1, u16* __restrict__ A2,
    u16* __restrict__ x0p, u16* __restrict__ x1p,
    u16* __restrict__ Bt1, u16* __restrict__ Bt2,
    u16* __restrict__ W0b, u16* __restrict__ W1b,
    float* __restrict__ hid, int* __restrict__ counts)
{
    const int b = blockIdx.x;
    const int tid = threadIdx.x;
    __shared__ float xr[4][256];

    if (b < PREP_B) {
        const int n0 = b * 4;
        #pragma unroll
        for (int t = 0; t < 4; ++t)
            xr[t][tid] = x[(size_t)(n0 + t) * 256 + tid];
        __syncthreads();
        #pragma unroll
        for (int t = 0; t < 4; ++t) {
            const int n = n0 + t;
            const float at = attrs[(size_t)n * 4 + (tid & 3)] * INV_SC;
            const int u = tid >> 2;
            A1[(size_t)n * 384 + 128 + tid] = f2bf(xr[t][u] * at);
            #pragma unroll
            for (int d = 0; d < 3; ++d)
                A2[((size_t)n * 3 + d) * 384 + 128 + tid] = f2bf(xr[t][64 + u * 3 + d] * at);
            if (tid < 64) {
                x0p[(size_t)n * 64 + tid] = f2bf(xr[t][tid]);
            } else {
                int q = tid - 64;
                int d = q >> 6, uu = q & 63;
                x1p[((size_t)n * 3 + d) * 64 + uu] = f2bf(xr[t][64 + uu * 3 + d]);
            }
        }
    } else if (b < PREP_B + WCONV_B) {
        int i = (b - PREP_B) * 256 + tid;
        if (i < 128 * 384) {
            int w = i / 384, k = i % 384;
            float v = (k < 128) ? W20[k * 128 + w] : Wsc0[(k - 128) * 128 + w];
            Bt1[i] = f2bf(v);
        } else if (i < 128 * 384 + 64 * 384) {
            int j = i - 128 * 384;
            int w = j / 384, k = j % 384;
            float v = (k < 128) ? W21[k * 64 + w] : Wsc1[(k - 128) * 64 + w];
            Bt2[j] = f2bf(v);
        } else if (i < 128 * 384 + 64 * 384 + 4096) {
            int j = i - (128 * 384 + 64 * 384);
            int v = j >> 6, u = j & 63;
            W0b[j] = f2bf(W0[u * 64 + v] * INV_SQRT_MUL);
        } else if (i < 128 * 384 + 64 * 384 + 8192) {
            int j = i - (128 * 384 + 64 * 384 + 4096);
            int v = j >> 6, u = j & 63;
            W1b[j] = f2bf(W1[u * 64 + v] * INV_SQRT_MUL);
        }
    } else if (b < PREP_B + WCONV_B + HID_B) {
        int i = (b - PREP_B - WCONV_B) * 256 + tid;
        int e = i >> 3, k = i & 7;
        float s = 0.f;
        #pragma unroll
        for (int j = 0; j < 8; ++j)
            s += eemb[(size_t)e * 8 + j] * Wm1[j * 8 + k];
        hid[i] = silu(s * INV_E);
    } else {
        int e = (b - PREP_B - WCONV_B - HID_B) * 256 + tid;
        if (e < E) atomicAdd(&counts[eidx[E + e]], 1);
    }
}

// ---------------------------------------------------------------------------
// Single-block scan over degree counts -> offsets + cursor
// ---------------------------------------------------------------------------
__global__ __launch_bounds__(1024) void k_scan(
    const int* __restrict__ counts, int* __restrict__ offsets,
    int* __restrict__ cursor)
{
    __shared__ int part[1024];
    const int tid = threadIdx.x;
    const int CH = 20;
    const int base = tid * CH;
    int s = 0;
    for (int i = 0; i < CH; ++i) {
        int idx = base + i;
        if (idx < N) s += counts[idx];
    }
    part[tid] = s;
    __syncthreads();
    for (int off = 1; off < 1024; off <<= 1) {
        int v = (tid >= off) ? part[tid - off] : 0;
        __syncthreads();
        part[tid] += v;
        __syncthreads();
    }
    int run = (tid > 0) ? part[tid - 1] : 0;
    for (int i = 0; i < CH; ++i) {
        int idx = base + i;
        if (idx < N) {
            int c = counts[idx];
            offsets[idx] = run;
            cursor[idx] = run;
            run += c;
        }
    }
    if (tid == 0) offsets[N] = part[1023];
}

// ---------------------------------------------------------------------------
// Mid kernel: [scatter | hgemm].
//   scatter: blocks [0, 625)    — perm build via cursor atomics
//   hgemm:   blocks [625, 1875) — lin1 MFMA GEMM -> hc bf16 AoS
// ---------------------------------------------------------------------------
__global__ __launch_bounds__(256) void k_mid(
    const int* __restrict__ eidx, int* __restrict__ cursor,
    int* __restrict__ perm,
    const u16* __restrict__ x0p, const u16* __restrict__ x1p,
    const u16* __restrict__ W0b, const u16* __restrict__ W1b,
    u16* __restrict__ hc)
{
    const int b = blockIdx.x;
    if (b < 625) {
        int e = b * 256 + threadIdx.x;
        if (e < E) {
            int pos = atomicAdd(&cursor[eidx[E + e]], 1);
            perm[pos] = e;
        }
        return;
    }
    const int lane = threadIdx.x & 63;
    const int g = (b - 625) * 4 + (threadIdx.x >> 6);
    const int quad = lane >> 4, l16 = lane & 15;
    const bool isC1 = (g >= 1250);
    const int row0 = isC1 ? (g - 1250) * 16 : g * 16;
    const u16* Ap = isC1 ? (x1p + (size_t)(row0 + l16) * 64)
                         : (x0p + (size_t)(row0 + l16) * 64);
    const u16* Bp = isC1 ? W1b : W0b;

    f32x4 acc[4] = {};
    #pragma unroll
    for (int k0 = 0; k0 < 64; k0 += 32) {
        bf16x8 a = *(const bf16x8*)(Ap + k0 + quad * 8);
        #pragma unroll
        for (int ct = 0; ct < 4; ++ct) {
            bf16x8 bb = *(const bf16x8*)(Bp + (size_t)(ct * 16 + l16) * 64 + k0 + quad * 8);
            acc[ct] = __builtin_amdgcn_mfma_f32_16x16x32_bf16(a, bb, acc[ct], 0, 0, 0);
        }
    }
    #pragma unroll
    for (int ct = 0; ct < 4; ++ct) {
        #pragma unroll
        for (int r = 0; r < 4; ++r) {
            int row = row0 + quad * 4 + r;
            int v = ct * 16 + l16;
            if (!isC1) {
                hc[(size_t)row * 256 + v * 4] = f2bf(acc[ct][r]);
            } else {
                int n = row / 3, d = row - 3 * (row / 3);
                hc[(size_t)n * 256 + v * 4 + 1 + d] = f2bf(acc[ct][r]);
            }
        }
    }
}

// ---------------------------------------------------------------------------
// Gather v4: one wave per dst node; ILP-2 over edges; Wm2 in registers;
// bf16 hc row gather. Writes bf16 A1/A2 cols 0..127 (scales folded).
// ---------------------------------------------------------------------------
__global__ __launch_bounds__(256) void k_gather(
    const int* __restrict__ perm, const int* __restrict__ offsets,
    const int* __restrict__ eidx,
    const float* __restrict__ eattr, const float* __restrict__ hid,
    const u32* __restrict__ hc2, const float* __restrict__ Wm2,
    u16* __restrict__ A1, u16* __restrict__ A2)
{
    const int lane = threadIdx.x & 63;
    const int n = blockIdx.x * 4 + (threadIdx.x >> 6);
    const int beg = offsets[n];
    const int end = offsets[n + 1];

    float wm0[8], wm1[8], wm2r[8], wm3[8];
    #pragma unroll
    for (int k = 0; k < 8; ++k) {
        wm0[k]  = Wm2[k * 256 + lane];
        wm1[k]  = Wm2[k * 256 + 64 + lane];
        wm2r[k] = Wm2[k * 256 + 128 + lane];
        wm3[k]  = Wm2[k * 256 + 192 + lane];
    }

    float acc0a = 0.f, acc0b = 0.f;
    float s1a[3] = {0.f, 0.f, 0.f}, s1b[3] = {0.f, 0.f, 0.f};

    for (int base = beg; base < end; base += 64) {
        const int cnt = min(64, end - base);
        int e_l = 0, src_l = 0;
        if (lane < cnt) {
            e_l = perm[base + lane];
            src_l = eidx[e_l];
        }
        for (int i = 0; i < cnt; i += 2) {
            const bool hasB = (i + 1 < cnt);
            const int iB = hasB ? i + 1 : i;
            const int eA = __shfl(e_l, i, 64);
            const int sA = __shfl(src_l, i, 64);
            const int eB = __shfl(e_l, iB, 64);
            const int sB = __shfl(src_l, iB, 64);

            // issue all 8 loads up front (2 independent streams)
            const float4 ea0 = ((const float4*)eattr)[eA];
            const float4 hA0 = ((const float4*)hid)[(size_t)eA * 2];
            const float4 hB0 = ((const float4*)hid)[(size_t)eA * 2 + 1];
            const uint2  hp0 = ((const uint2*)hc2)[(size_t)sA * 64 + lane];
            float4 ea1 = ((const float4*)eattr)[eB];
            const float4 hA1 = ((const float4*)hid)[(size_t)eB * 2];
            const float4 hB1 = ((const float4*)hid)[(size_t)eB * 2 + 1];
            const uint2  hp1 = ((const uint2*)hc2)[(size_t)sB * 64 + lane];
            if (!hasB) ea1 = make_float4(0.f, 0.f, 0.f, 0.f);  // nulls edge B

            // ---- edge A ----
            {
                float w1 = hA0.x*wm0[0]+hA0.y*wm0[1]+hA0.z*wm0[2]+hA0.w*wm0[3]
                         + hB0.x*wm0[4]+hB0.y*wm0[5]+hB0.z*wm0[6]+hB0.w*wm0[7];
                float w2 = hA0.x*wm1[0]+hA0.y*wm1[1]+hA0.z*wm1[2]+hA0.w*wm1[3]
                         + hB0.x*wm1[4]+hB0.y*wm1[5]+hB0.z*wm1[6]+hB0.w*wm1[7];
                float w3 = hA0.x*wm2r[0]+hA0.y*wm2r[1]+hA0.z*wm2r[2]+hA0.w*wm2r[3]
                         + hB0.x*wm2r[4]+hB0.y*wm2r[5]+hB0.z*wm2r[6]+hB0.w*wm2r[7];
                float w4 = hA0.x*wm3[0]+hA0.y*wm3[1]+hA0.z*wm3[2]+hA0.w*wm3[3]
                         + hB0.x*wm3[4]+hB0.y*wm3[5]+hB0.z*wm3[6]+hB0.w*wm3[7];
                const float g0 = bflo(hp0.x), g1x = bfhi(hp0.x);
                const float g1y = bflo(hp0.y), g1z = bfhi(hp0.y);
                acc0a += w1 * g0 * ea0.x;
                acc0b += w4 * (g1x * ea0.y + g1y * ea0.z + g1z * ea0.w);
                const float wg = w2 * g0, w3a = w3 * ea0.x;
                s1a[0] += wg * ea0.y;  s1a[1] += wg * ea0.z;  s1a[2] += wg * ea0.w;
                s1b[0] += w3a * g1x;   s1b[1] += w3a * g1y;   s1b[2] += w3a * g1z;
            }
            // ---- edge B ----
            {
                float w1 = hA1.x*wm0[0]+hA1.y*wm0[1]+hA1.z*wm0[2]+hA1.w*wm0[3]
                         + hB1.x*wm0[4]+hB1.y*wm0[5]+hB1.z*wm0[6]+hB1.w*wm0[7];
                float w2 = hA1.x*wm1[0]+hA1.y*wm1[1]+hA1.z*wm1[2]+hA1.w*wm1[3]
                         + hB1.x*wm1[4]+hB1.y*wm1[5]+hB1.z*wm1[6]+hB1.w*wm1[7];
                float w3 = hA1.x*wm2r[0]+hA1.y*wm2r[1]+hA1.z*wm2r[2]+hA1.w*wm2r[3]
                         + hB1.x*wm2r[4]+hB1.y*wm2r[5]+hB1.z*wm2r[6]+hB1.w*wm2r[7];
                float w4 = hA1.x*wm3[0]+hA1.y*wm3[1]+hA1.z*wm3[2]+hA1.w*wm3[3]
                         + hB1.x*wm3[4]+hB1.y*wm3[5]+hB1.z*wm3[6]+hB1.w*wm3[7];
                const float g0 = bflo(hp1.x), g1x = bfhi(hp1.x);
                const float g1y = bflo(hp1.y), g1z = bfhi(hp1.y);
                acc0a += w1 * g0 * ea1.x;
                acc0b += w4 * (g1x * ea1.y + g1y * ea1.z + g1z * ea1.w);
                const float wg = w2 * g0, w3a = w3 * ea1.x;
                s1a[0] += wg * ea1.y;  s1a[1] += wg * ea1.z;  s1a[2] += wg * ea1.w;
                s1b[0] += w3a * g1x;   s1b[1] += w3a * g1y;   s1b[2] += w3a * g1z;
            }
        }
    }

    const float f = INV_E * INV_N * INV2;
    u16* a1p = &A1[(size_t)n * 384];
    a1p[lane]      = f2bf(acc0a * f);
    a1p[64 + lane] = f2bf(acc0b * f * INV_SQRT3);
    #pragma unroll
    for (int d = 0; d < 3; ++d) {
        u16* a2p = &A2[((size_t)n * 3 + d) * 384];
        a2p[lane]      = f2bf(s1a[d] * f);
        a2p[64 + lane] = f2bf(s1b[d] * f);
    }
}

// ---------------------------------------------------------------------------
// Fused post-GEMM + epilogue v3: 16 nodes/block, register double-buffered
// K-loop (cur/nxt fragment arrays), epilogue x prefetched into registers.
// ---------------------------------------------------------------------------
__global__ __launch_bounds__(256) void k_gemm_fused(
    const u16* __restrict__ A1, const u16* __restrict__ A2,
    const u16* __restrict__ Bt1, const u16* __restrict__ Bt2,
    const float* __restrict__ x, float* __restrict__ out)
{
    const int lane = threadIdx.x & 63;
    const int wave = threadIdx.x >> 6;
    const int quad = lane >> 4, l16 = lane & 15;
    const int n0 = blockIdx.x * 16;

    __shared__ float st0[16][130];
    __shared__ float st1[48][66];

    const u16* ptr[7];
    ptr[0] = A1  + (size_t)(n0 + l16) * 384 + quad * 8;            // a0
    ptr[1] = Bt1 + (size_t)(wave * 16 + l16) * 384 + quad * 8;     // b0
    ptr[2] = Bt1 + (size_t)((wave + 4) * 16 + l16) * 384 + quad * 8; // b1
    ptr[3] = A2  + (size_t)(3 * n0 + l16) * 384 + quad * 8;        // a1
    ptr[4] = A2  + (size_t)(3 * n0 + 16 + l16) * 384 + quad * 8;   // a2
    ptr[5] = A2  + (size_t)(3 * n0 + 32 + l16) * 384 + quad * 8;   // a3
    ptr[6] = Bt2 + (size_t)(wave * 16 + l16) * 384 + quad * 8;     // b2

    bf16x8 cur[7], nxt[7];
    #pragma unroll
    for (int j = 0; j < 7; ++j) cur[j] = *(const bf16x8*)(ptr[j]);

    // epilogue x prefetch (independent, drains during K-loop)
    float xv[16];
    #pragma unroll
    for (int i = 0; i < 16; ++i)
        xv[i] = x[(size_t)(n0 + i) * 256 + threadIdx.x];

    f32x4 acc0 = {}, acc1 = {}, acc2 = {}, acc3 = {}, acc4 = {};
    #pragma unroll
    for (int k0 = 0; k0 < 384; k0 += 32) {
        if (k0 + 32 < 384) {
            #pragma unroll
            for (int j = 0; j < 7; ++j)
                nxt[j] = *(const bf16x8*)(ptr[j] + k0 + 32);
        }
        acc0 = __builtin_amdgcn_mfma_f32_16x16x32_bf16(cur[0], cur[1], acc0, 0, 0, 0);
        acc1 = __builtin_amdgcn_mfma_f32_16x16x32_bf16(cur[0], cur[2], acc1, 0, 0, 0);
        acc2 = __builtin_amdgcn_mfma_f32_16x16x32_bf16(cur[3], cur[6], acc2, 0, 0, 0);
        acc3 = __builtin_amdgcn_mfma_f32_16x16x32_bf16(cur[4], cur[6], acc3, 0, 0, 0);
        acc4 = __builtin_amdgcn_mfma_f32_16x16x32_bf16(cur[5], cur[6], acc4, 0, 0, 0);
        #pragma unroll
        for (int j = 0; j < 7; ++j) cur[j] = nxt[j];
    }
    #pragma unroll
    for (int r = 0; r < 4; ++r) {
        st0[quad * 4 + r][wave * 16 + l16]       = acc0[r];
        st0[quad * 4 + r][(wave + 4) * 16 + l16] = acc1[r];
        st1[quad * 4 + r][wave * 16 + l16]       = acc2[r];
        st1[16 + quad * 4 + r][wave * 16 + l16]  = acc3[r];
        st1[32 + quad * 4 + r][wave * 16 + l16]  = acc4[r];
    }
    __syncthreads();

    const int c = threadIdx.x;
    #pragma unroll
    for (int t = 0; t < 16; ++t) {
        float o;
        if (c < 64) {
            o = xv[t] + silu(st0[t][c]);
        } else {
            int r = c - 64;
            int w = (r * 21846) >> 16;      // r/3
            int d = r - w * 3;
            o = xv[t] + silu(st0[t][64 + w]) * st1[t * 3 + d][w];
        }
        out[(size_t)(n0 + t) * 256 + c] = o;
    }
}

extern "C" void kernel_launch(void* const* d_in, const int* in_sizes, int n_in,
                              void* d_out, int out_size, void* d_ws, size_t ws_size,
                              hipStream_t stream) {
    const float* node_feats = (const float*)d_in[0];
    const float* node_attrs = (const float*)d_in[1];
    const float* edge_attrs = (const float*)d_in[2];
    const float* edge_emb   = (const float*)d_in[3];
    const float* W_lin1_0   = (const float*)d_in[4];
    const float* W_lin1_1   = (const float*)d_in[5];
    const float* W_mlp1     = (const float*)d_in[6];
    const float* W_mlp2     = (const float*)d_in[7];
    const float* W_lin2_0   = (const float*)d_in[8];
    const float* W_lin2_1   = (const float*)d_in[9];
    const float* W_sc0      = (const float*)d_in[10];
    const float* W_sc1      = (const float*)d_in[11];
    const int*   edge_index = (const int*)d_in[12];
    float* out = (float*)d_out;

    char* p = (char*)d_ws;
    float* hid = (float*)p;                 p += (size_t)E * 8 * 4;
    u16* hc    = (u16*)p;                   p += (size_t)N * 256 * 2;
    u16* A1    = (u16*)p;                   p += (size_t)N * 384 * 2;
    u16* A2    = (u16*)p;                   p += (size_t)N * 3 * 384 * 2;
    u16* x0p   = (u16*)p;                   p += (size_t)N * 64 * 2;
    u16* x1p   = (u16*)p;                   p += (size_t)N * 3 * 64 * 2;
    u16* Bt1   = (u16*)p;                   p += 128 * 384 * 2;
    u16* Bt2   = (u16*)p;                   p += 64 * 384 * 2;
    u16* W0b   = (u16*)p;                   p += 4096 * 2;
    u16* W1b   = (u16*)p;                   p += 4096 * 2;
    int* counts  = (int*)p;                 p += N * 4;
    int* offsets = (int*)p;                 p += (N + 1) * 4;
    int* perm    = (int*)p;                 p += E * 4;

    hipMemsetAsync(counts, 0, N * sizeof(int), stream);

    k_front<<<PREP_B + WCONV_B + HID_B + HIST_B, 256, 0, stream>>>(
        node_feats, node_attrs, edge_emb, edge_index,
        W_lin2_0, W_sc0, W_lin2_1, W_sc1, W_lin1_0, W_lin1_1, W_mlp1,
        A1, A2, x0p, x1p, Bt1, Bt2, W0b, W1b, hid, counts);
    k_scan<<<1, 1024, 0, stream>>>(counts, offsets, counts);
    k_mid<<<1875, 256, 0, stream>>>(edge_index, counts, perm,
                                    x0p, x1p, W0b, W1b, hc);
    k_gather<<<N / 4, 256, 0, stream>>>(perm, offsets, edge_index,
                                        edge_attrs, hid, (const u32*)hc,
                                        W_mlp2, A1, A2);
    k_gemm_fused<<<1250, 256, 0, stream>>>(A1, A2, Bt1, Bt2, node_feats, out);
}

// Round 8
// 255.015 us; speedup vs baseline: 2.1451x; 1.0390x over previous
//
#include <hip/hip_runtime.h>
#include <hip/hip_bf16.h>
#include <math.h>

#define N 20000
#define E 160000
#define MUL 64
#define EDIM 8
#define NZ 4

#define INV_SQRT_MUL 0.125f          // 1/sqrt(64)
#define INV_E 0.35355339059327373f   // 1/sqrt(8)
#define INV_N 0.35355339059327373f   // 1/sqrt(8)
#define INV2 0.08838834764831845f    // 1/sqrt(128)
#define INV_SC 0.0625f               // 1/sqrt(256)
#define INV_SQRT3 0.5773502691896258f

typedef unsigned short u16;
typedef unsigned int u32;
typedef short bf16x8 __attribute__((ext_vector_type(8)));
typedef float f32x4 __attribute__((ext_vector_type(4)));

__device__ __forceinline__ float silu(float v) {
    return v / (1.0f + __expf(-v));
}

__device__ __forceinline__ u16 f2bf(float f) {
    union { float f; unsigned int u; } v; v.f = f;
    unsigned int r = (v.u + 0x7FFFu + ((v.u >> 16) & 1u)) >> 16;
    return (u16)r;
}
__device__ __forceinline__ float bflo(u32 p) {
    union { unsigned int u; float f; } v; v.u = p << 16; return v.f;
}
__device__ __forceinline__ float bfhi(u32 p) {
    union { unsigned int u; float f; } v; v.u = p & 0xFFFF0000u; return v.f;
}

#define MFMA(a, b, c) __builtin_amdgcn_mfma_f32_16x16x32_bf16(a, b, c, 0, 0, 0)

// A1: [N][192]   cols 0..127 = gathered s0 (scaled), 128..191 = bf16(x0)
// A2: [3N][192]  cols 0..127 = gathered s1,          128..191 = bf16(x1[:,d])
// Bt1m [128][128], Bt1z [4][128][64] (INV_SC folded), Bt2m [64][128],
// Bt2z [4][64][64] (INV_SC folded), W0b/W1b [64][64] (INV_SQRT_MUL folded)

// ---------------------------------------------------------------------------
// Front: grid-partitioned [prep | wconv | hid | hist]
// ---------------------------------------------------------------------------
#define PREP_B  5000
#define WCONV_B 320
#define HID_B   5000
#define HIST_B  625

__global__ __launch_bounds__(256) void k_front(
    const float* __restrict__ x,
    const float* __restrict__ eemb, const int* __restrict__ eidx,
    const float* __restrict__ W20, const float* __restrict__ Wsc0,
    const float* __restrict__ W21, const float* __restrict__ Wsc1,
    const float* __restrict__ W0, const float* __restrict__ W1,
    const float* __restrict__ Wm1,
    u16* __restrict__ A1, u16* __restrict__ A2,
    u16* __restrict__ Bt1m, u16* __restrict__ Bt1z,
    u16* __restrict__ Bt2m, u16* __restrict__ Bt2z,
    u16* __restrict__ W0b, u16* __restrict__ W1b,
    float* __restrict__ hid, int* __restrict__ counts)
{
    const int b = blockIdx.x;
    const int tid = threadIdx.x;
    __shared__ float xr[4][256];

    if (b < PREP_B) {
        const int n0 = b * 4;
        #pragma unroll
        for (int t = 0; t < 4; ++t)
            xr[t][tid] = x[(size_t)(n0 + t) * 256 + tid];
        __syncthreads();
        #pragma unroll
        for (int t = 0; t < 4; ++t) {
            const int n = n0 + t;
            if (tid < 64) {
                A1[(size_t)n * 192 + 128 + tid] = f2bf(xr[t][tid]);
            } else {
                int q = tid - 64;
                int d = q >> 6, u = q & 63;
                A2[((size_t)n * 3 + d) * 192 + 128 + u] = f2bf(xr[t][64 + u * 3 + d]);
            }
        }
    } else if (b < PREP_B + WCONV_B) {
        int i = (b - PREP_B) * 256 + tid;
        if (i < 16384) {                               // Bt1m[w][k]
            int w = i >> 7, k = i & 127;
            Bt1m[i] = f2bf(W20[k * 128 + w]);
        } else if (i < 49152) {                        // Bt1z[z][w][k]
            int j = i - 16384;
            int z = j >> 13, r = j & 8191, w = r >> 6, k = r & 63;
            Bt1z[j] = f2bf(Wsc0[(k * 4 + z) * 128 + w] * INV_SC);
        } else if (i < 57344) {                        // Bt2m[w][k]
            int j = i - 49152;
            int w = j >> 7, k = j & 127;
            Bt2m[j] = f2bf(W21[k * 64 + w]);
        } else if (i < 73728) {                        // Bt2z[z][w][k]
            int j = i - 57344;
            int z = j >> 12, r = j & 4095, w = r >> 6, k = r & 63;
            Bt2z[j] = f2bf(Wsc1[(k * 4 + z) * 64 + w] * INV_SC);
        } else if (i < 77824) {                        // W0b[v][u]
            int j = i - 73728;
            int v = j >> 6, u = j & 63;
            W0b[j] = f2bf(W0[u * 64 + v] * INV_SQRT_MUL);
        } else {                                       // W1b[v][u]
            int j = i - 77824;
            int v = j >> 6, u = j & 63;
            W1b[j] = f2bf(W1[u * 64 + v] * INV_SQRT_MUL);
        }
    } else if (b < PREP_B + WCONV_B + HID_B) {
        int i = (b - PREP_B - WCONV_B) * 256 + tid;
        int e = i >> 3, k = i & 7;
        float s = 0.f;
        #pragma unroll
        for (int j = 0; j < 8; ++j)
            s += eemb[(size_t)e * 8 + j] * Wm1[j * 8 + k];
        hid[i] = silu(s * INV_E);
    } else {
        int e = (b - PREP_B - WCONV_B - HID_B) * 256 + tid;
        if (e < E) atomicAdd(&counts[eidx[E + e]], 1);
    }
}

// ---------------------------------------------------------------------------
// Single-block scan
// ---------------------------------------------------------------------------
__global__ __launch_bounds__(1024) void k_scan(
    const int* __restrict__ counts, int* __restrict__ offsets,
    int* __restrict__ cursor)
{
    __shared__ int part[1024];
    const int tid = threadIdx.x;
    const int CH = 20;
    const int base = tid * CH;
    int s = 0;
    for (int i = 0; i < CH; ++i) {
        int idx = base + i;
        if (idx < N) s += counts[idx];
    }
    part[tid] = s;
    __syncthreads();
    for (int off = 1; off < 1024; off <<= 1) {
        int v = (tid >= off) ? part[tid - off] : 0;
        __syncthreads();
        part[tid] += v;
        __syncthreads();
    }
    int run = (tid > 0) ? part[tid - 1] : 0;
    for (int i = 0; i < CH; ++i) {
        int idx = base + i;
        if (idx < N) {
            int c = counts[idx];
            offsets[idx] = run;
            cursor[idx] = run;
            run += c;
        }
    }
    if (tid == 0) offsets[N] = part[1023];
}

// ---------------------------------------------------------------------------
// Mid: [scatter (perm_e + perm_src) | hgemm from A tails -> hc bf16 AoS]
// ---------------------------------------------------------------------------
__global__ __launch_bounds__(256) void k_mid(
    const int* __restrict__ eidx, int* __restrict__ cursor,
    int* __restrict__ perm_e, int* __restrict__ perm_src,
    const u16* __restrict__ A1, const u16* __restrict__ A2,
    const u16* __restrict__ W0b, const u16* __restrict__ W1b,
    u16* __restrict__ hc)
{
    const int b = blockIdx.x;
    if (b < 625) {
        int e = b * 256 + threadIdx.x;
        if (e < E) {
            int src = eidx[e];
            int pos = atomicAdd(&cursor[eidx[E + e]], 1);
            perm_e[pos] = e;
            perm_src[pos] = src;
        }
        return;
    }
    const int lane = threadIdx.x & 63;
    const int g = (b - 625) * 4 + (threadIdx.x >> 6);
    const int quad = lane >> 4, l16 = lane & 15;
    const bool isC1 = (g >= 1250);
    const int row0 = isC1 ? (g - 1250) * 16 : g * 16;
    const u16* Ap = isC1 ? (A2 + (size_t)(row0 + l16) * 192 + 128)
                         : (A1 + (size_t)(row0 + l16) * 192 + 128);
    const u16* Bp = isC1 ? W1b : W0b;

    f32x4 acc[4] = {};
    #pragma unroll
    for (int k0 = 0; k0 < 64; k0 += 32) {
        bf16x8 a = *(const bf16x8*)(Ap + k0 + quad * 8);
        #pragma unroll
        for (int ct = 0; ct < 4; ++ct) {
            bf16x8 bb = *(const bf16x8*)(Bp + (size_t)(ct * 16 + l16) * 64 + k0 + quad * 8);
            acc[ct] = MFMA(a, bb, acc[ct]);
        }
    }
    #pragma unroll
    for (int ct = 0; ct < 4; ++ct) {
        #pragma unroll
        for (int r = 0; r < 4; ++r) {
            int row = row0 + quad * 4 + r;
            int v = ct * 16 + l16;
            if (!isC1) {
                hc[(size_t)row * 256 + v * 4] = f2bf(acc[ct][r]);
            } else {
                int n = row / 3, d = row - 3 * (row / 3);
                hc[(size_t)n * 256 + v * 4 + 1 + d] = f2bf(acc[ct][r]);
            }
        }
    }
}

// ---------------------------------------------------------------------------
// Gather: one wave per dst node; ILP-2; Wm2 in regs; pre-resolved src.
// Writes bf16 into A1/A2 cols 0..127 (scales folded).
// ---------------------------------------------------------------------------
__global__ __launch_bounds__(256) void k_gather(
    const int* __restrict__ perm_e, const int* __restrict__ perm_src,
    const int* __restrict__ offsets,
    const float* __restrict__ eattr, const float* __restrict__ hid,
    const u32* __restrict__ hc2, const float* __restrict__ Wm2,
    u16* __restrict__ A1, u16* __restrict__ A2)
{
    const int lane = threadIdx.x & 63;
    const int n = blockIdx.x * 4 + (threadIdx.x >> 6);
    const int beg = offsets[n];
    const int end = offsets[n + 1];

    float wm0[8], wm1[8], wm2r[8], wm3[8];
    #pragma unroll
    for (int k = 0; k < 8; ++k) {
        wm0[k]  = Wm2[k * 256 + lane];
        wm1[k]  = Wm2[k * 256 + 64 + lane];
        wm2r[k] = Wm2[k * 256 + 128 + lane];
        wm3[k]  = Wm2[k * 256 + 192 + lane];
    }

    float acc0a = 0.f, acc0b = 0.f;
    float s1a[3] = {0.f, 0.f, 0.f}, s1b[3] = {0.f, 0.f, 0.f};

    for (int base = beg; base < end; base += 64) {
        const int cnt = min(64, end - base);
        int e_l = 0, src_l = 0;
        if (lane < cnt) {
            e_l = perm_e[base + lane];
            src_l = perm_src[base + lane];
        }
        for (int i = 0; i < cnt; i += 2) {
            const bool hasB = (i + 1 < cnt);
            const int iB = hasB ? i + 1 : i;
            const int eA = __shfl(e_l, i, 64);
            const int sA = __shfl(src_l, i, 64);
            const int eB = __shfl(e_l, iB, 64);
            const int sB = __shfl(src_l, iB, 64);

            const float4 ea0 = ((const float4*)eattr)[eA];
            const float4 hA0 = ((const float4*)hid)[(size_t)eA * 2];
            const float4 hB0 = ((const float4*)hid)[(size_t)eA * 2 + 1];
            const uint2  hp0 = ((const uint2*)hc2)[(size_t)sA * 64 + lane];
            float4 ea1 = ((const float4*)eattr)[eB];
            const float4 hA1 = ((const float4*)hid)[(size_t)eB * 2];
            const float4 hB1 = ((const float4*)hid)[(size_t)eB * 2 + 1];
            const uint2  hp1 = ((const uint2*)hc2)[(size_t)sB * 64 + lane];
            if (!hasB) ea1 = make_float4(0.f, 0.f, 0.f, 0.f);

            {
                float w1 = hA0.x*wm0[0]+hA0.y*wm0[1]+hA0.z*wm0[2]+hA0.w*wm0[3]
                         + hB0.x*wm0[4]+hB0.y*wm0[5]+hB0.z*wm0[6]+hB0.w*wm0[7];
                float w2 = hA0.x*wm1[0]+hA0.y*wm1[1]+hA0.z*wm1[2]+hA0.w*wm1[3]
                         + hB0.x*wm1[4]+hB0.y*wm1[5]+hB0.z*wm1[6]+hB0.w*wm1[7];
                float w3 = hA0.x*wm2r[0]+hA0.y*wm2r[1]+hA0.z*wm2r[2]+hA0.w*wm2r[3]
                         + hB0.x*wm2r[4]+hB0.y*wm2r[5]+hB0.z*wm2r[6]+hB0.w*wm2r[7];
                float w4 = hA0.x*wm3[0]+hA0.y*wm3[1]+hA0.z*wm3[2]+hA0.w*wm3[3]
                         + hB0.x*wm3[4]+hB0.y*wm3[5]+hB0.z*wm3[6]+hB0.w*wm3[7];
                const float g0 = bflo(hp0.x), g1x = bfhi(hp0.x);
                const float g1y = bflo(hp0.y), g1z = bfhi(hp0.y);
                acc0a += w1 * g0 * ea0.x;
                acc0b += w4 * (g1x * ea0.y + g1y * ea0.z + g1z * ea0.w);
                const float wg = w2 * g0, w3a = w3 * ea0.x;
                s1a[0] += wg * ea0.y;  s1a[1] += wg * ea0.z;  s1a[2] += wg * ea0.w;
                s1b[0] += w3a * g1x;   s1b[1] += w3a * g1y;   s1b[2] += w3a * g1z;
            }
            {
                float w1 = hA1.x*wm0[0]+hA1.y*wm0[1]+hA1.z*wm0[2]+hA1.w*wm0[3]
                         + hB1.x*wm0[4]+hB1.y*wm0[5]+hB1.z*wm0[6]+hB1.w*wm0[7];
                float w2 = hA1.x*wm1[0]+hA1.y*wm1[1]+hA1.z*wm1[2]+hA1.w*wm1[3]
                         + hB1.x*wm1[4]+hB1.y*wm1[5]+hB1.z*wm1[6]+hB1.w*wm1[7];
                float w3 = hA1.x*wm2r[0]+hA1.y*wm2r[1]+hA1.z*wm2r[2]+hA1.w*wm2r[3]
                         + hB1.x*wm2r[4]+hB1.y*wm2r[5]+hB1.z*wm2r[6]+hB1.w*wm2r[7];
                float w4 = hA1.x*wm3[0]+hA1.y*wm3[1]+hA1.z*wm3[2]+hA1.w*wm3[3]
                         + hB1.x*wm3[4]+hB1.y*wm3[5]+hB1.z*wm3[6]+hB1.w*wm3[7];
                const float g0 = bflo(hp1.x), g1x = bfhi(hp1.x);
                const float g1y = bflo(hp1.y), g1z = bfhi(hp1.y);
                acc0a += w1 * g0 * ea1.x;
                acc0b += w4 * (g1x * ea1.y + g1y * ea1.z + g1z * ea1.w);
                const float wg = w2 * g0, w3a = w3 * ea1.x;
                s1a[0] += wg * ea1.y;  s1a[1] += wg * ea1.z;  s1a[2] += wg * ea1.w;
                s1b[0] += w3a * g1x;   s1b[1] += w3a * g1y;   s1b[2] += w3a * g1z;
            }
        }
    }

    const float f = INV_E * INV_N * INV2;
    u16* a1p = &A1[(size_t)n * 192];
    a1p[lane]      = f2bf(acc0a * f);
    a1p[64 + lane] = f2bf(acc0b * f * INV_SQRT3);
    #pragma unroll
    for (int d = 0; d < 3; ++d) {
        u16* a2p = &A2[((size_t)n * 3 + d) * 192];
        a2p[lane]      = f2bf(s1a[d] * f);
        a2p[64 + lane] = f2bf(s1b[d] * f);
    }
}

// ---------------------------------------------------------------------------
// Fused post-GEMM + epilogue v4: 16 nodes/block, 192-col A, z-sliced sc
// accumulators combined with attr in the epilogue.
// ---------------------------------------------------------------------------
__global__ __launch_bounds__(256) void k_gemm_fused(
    const u16* __restrict__ A1, const u16* __restrict__ A2,
    const u16* __restrict__ Bt1m, const u16* __restrict__ Bt1z,
    const u16* __restrict__ Bt2m, const u16* __restrict__ Bt2z,
    const float* __restrict__ attrs, const float* __restrict__ x,
    float* __restrict__ out)
{
    const int lane = threadIdx.x & 63;
    const int wave = threadIdx.x >> 6;
    const int quad = lane >> 4, l16 = lane & 15;
    const int n0 = blockIdx.x * 16;

    __shared__ float st0[16][132];
    __shared__ float st1[48][68];
    __shared__ float sat[16][4];
    if (threadIdx.x < 64)
        sat[threadIdx.x >> 2][threadIdx.x & 3] =
            attrs[(size_t)(n0 + (threadIdx.x >> 2)) * 4 + (threadIdx.x & 3)];

    const u16* a0p = A1 + (size_t)(n0 + l16) * 192 + quad * 8;
    const u16* a1p = A2 + (size_t)(3 * n0 + l16) * 192 + quad * 8;
    const u16* a2p = a1p + 16 * 192;
    const u16* a3p = a1p + 32 * 192;
    const u16* b0p = Bt1m + (size_t)(wave * 16 + l16) * 128 + quad * 8;
    const u16* b1p = Bt1m + (size_t)((wave + 4) * 16 + l16) * 128 + quad * 8;
    const u16* b2p = Bt2m + (size_t)(wave * 16 + l16) * 128 + quad * 8;
    const u16* bz0p = Bt1z + (size_t)(wave * 16 + l16) * 64 + quad * 8;
    const u16* bz1p = Bt1z + (size_t)((wave + 4) * 16 + l16) * 64 + quad * 8;
    const u16* bz2p = Bt2z + (size_t)(wave * 16 + l16) * 64 + quad * 8;

    f32x4 m0 = {}, m1 = {}, m2 = {}, m3 = {}, m4 = {};
    f32x4 z0[4] = {}, z1[4] = {}, z2[4] = {}, z3[4] = {}, z4[4] = {};

    #pragma unroll
    for (int kt = 0; kt < 4; ++kt) {
        const int ko = kt * 32;
        bf16x8 a0 = *(const bf16x8*)(a0p + ko);
        bf16x8 a1 = *(const bf16x8*)(a1p + ko);
        bf16x8 a2 = *(const bf16x8*)(a2p + ko);
        bf16x8 a3 = *(const bf16x8*)(a3p + ko);
        bf16x8 b0 = *(const bf16x8*)(b0p + ko);
        bf16x8 b1 = *(const bf16x8*)(b1p + ko);
        bf16x8 b2 = *(const bf16x8*)(b2p + ko);
        m0 = MFMA(a0, b0, m0);
        m1 = MFMA(a0, b1, m1);
        m2 = MFMA(a1, b2, m2);
        m3 = MFMA(a2, b2, m3);
        m4 = MFMA(a3, b2, m4);
    }
    #pragma unroll
    for (int kt = 0; kt < 2; ++kt) {
        const int ao = 128 + kt * 32;
        const int ko = kt * 32;
        bf16x8 a0 = *(const bf16x8*)(a0p + ao);
        bf16x8 a1 = *(const bf16x8*)(a1p + ao);
        bf16x8 a2 = *(const bf16x8*)(a2p + ao);
        bf16x8 a3 = *(const bf16x8*)(a3p + ao);
        #pragma unroll
        for (int z = 0; z < 4; ++z) {
            bf16x8 c0 = *(const bf16x8*)(bz0p + z * 8192 + ko);
            bf16x8 c1 = *(const bf16x8*)(bz1p + z * 8192 + ko);
            bf16x8 c2 = *(const bf16x8*)(bz2p + z * 4096 + ko);
            z0[z] = MFMA(a0, c0, z0[z]);
            z1[z] = MFMA(a0, c1, z1[z]);
            z2[z] = MFMA(a1, c2, z2[z]);
            z3[z] = MFMA(a2, c2, z3[z]);
            z4[z] = MFMA(a3, c2, z4[z]);
        }
    }
    __syncthreads();   // sat visible to all

    #pragma unroll
    for (int r = 0; r < 4; ++r) {
        const int r0 = quad * 4 + r;
        const float t0a = sat[r0][0], t0b = sat[r0][1],
                    t0c = sat[r0][2], t0d = sat[r0][3];
        st0[r0][wave * 16 + l16] =
            m0[r] + t0a * z0[0][r] + t0b * z0[1][r] + t0c * z0[2][r] + t0d * z0[3][r];
        st0[r0][(wave + 4) * 16 + l16] =
            m1[r] + t0a * z1[0][r] + t0b * z1[1][r] + t0c * z1[2][r] + t0d * z1[3][r];
        #pragma unroll
        for (int rt = 0; rt < 3; ++rt) {
            const int idx = rt * 16 + r0;            // 0..47
            const int nl = (idx * 21846) >> 16;      // idx/3
            const float za = sat[nl][0], zb = sat[nl][1],
                        zc = sat[nl][2], zd = sat[nl][3];
            const f32x4* zm = (rt == 0) ? z2 : (rt == 1) ? z3 : z4;
            const float mm = (rt == 0) ? m2[r] : (rt == 1) ? m3[r] : m4[r];
            st1[idx][wave * 16 + l16] =
                mm + za * zm[0][r] + zb * zm[1][r] + zc * zm[2][r] + zd * zm[3][r];
        }
    }
    __syncthreads();

    const int c = threadIdx.x;
    #pragma unroll
    for (int t = 0; t < 16; ++t) {
        const float xv = x[(size_t)(n0 + t) * 256 + c];
        float o;
        if (c < 64) {
            o = xv + silu(st0[t][c]);
        } else {
            int r = c - 64;
            int w = (r * 21846) >> 16;      // r/3
            int d = r - w * 3;
            o = xv + silu(st0[t][64 + w]) * st1[t * 3 + d][w];
        }
        out[(size_t)(n0 + t) * 256 + c] = o;
    }
}

extern "C" void kernel_launch(void* const* d_in, const int* in_sizes, int n_in,
                              void* d_out, int out_size, void* d_ws, size_t ws_size,
                              hipStream_t stream) {
    const float* node_feats = (const float*)d_in[0];
    const float* node_attrs = (const float*)d_in[1];
    const float* edge_attrs = (const float*)d_in[2];
    const float* edge_emb   = (const float*)d_in[3];
    const float* W_lin1_0   = (const float*)d_in[4];
    const float* W_lin1_1   = (const float*)d_in[5];
    const float* W_mlp1     = (const float*)d_in[6];
    const float* W_mlp2     = (const float*)d_in[7];
    const float* W_lin2_0   = (const float*)d_in[8];
    const float* W_lin2_1   = (const float*)d_in[9];
    const float* W_sc0      = (const float*)d_in[10];
    const float* W_sc1      = (const float*)d_in[11];
    const int*   edge_index = (const int*)d_in[12];
    float* out = (float*)d_out;

    char* p = (char*)d_ws;
    float* hid = (float*)p;                 p += (size_t)E * 8 * 4;
    u16* hc    = (u16*)p;                   p += (size_t)N * 256 * 2;
    u16* A1    = (u16*)p;                   p += (size_t)N * 192 * 2;
    u16* A2    = (u16*)p;                   p += (size_t)N * 3 * 192 * 2;
    u16* Bt1m  = (u16*)p;                   p += 16384 * 2;
    u16* Bt1z  = (u16*)p;                   p += 32768 * 2;
    u16* Bt2m  = (u16*)p;                   p += 8192 * 2;
    u16* Bt2z  = (u16*)p;                   p += 16384 * 2;
    u16* W0b   = (u16*)p;                   p += 4096 * 2;
    u16* W1b   = (u16*)p;                   p += 4096 * 2;
    int* counts   = (int*)p;                p += N * 4;
    int* offsets  = (int*)p;                p += (N + 1) * 4;
    int* perm_e   = (int*)p;                p += E * 4;
    int* perm_src = (int*)p;                p += E * 4;

    hipMemsetAsync(counts, 0, N * sizeof(int), stream);

    k_front<<<PREP_B + WCONV_B + HID_B + HIST_B, 256, 0, stream>>>(
        node_feats, edge_emb, edge_index,
        W_lin2_0, W_sc0, W_lin2_1, W_sc1, W_lin1_0, W_lin1_1, W_mlp1,
        A1, A2, Bt1m, Bt1z, Bt2m, Bt2z, W0b, W1b, hid, counts);
    k_scan<<<1, 1024, 0, stream>>>(counts, offsets, counts);
    k_mid<<<1875, 256, 0, stream>>>(edge_index, counts, perm_e, perm_src,
                                    A1, A2, W0b, W1b, hc);
    k_gather<<<N / 4, 256, 0, stream>>>(perm_e, perm_src, offsets,
                                        edge_attrs, hid, (const u32*)hc,
                                        W_mlp2, A1, A2);
    k_gemm_fused<<<1250, 256, 0, stream>>>(A1, A2, Bt1m, Bt1z, Bt2m, Bt2z,
                                           node_attrs, node_feats, out);
}